// Round 1
// baseline (2950.740 us; speedup 1.0000x reference)
//
#include <hip/hip_runtime.h>

#define ND 16384
#define BATCH 4096
#define CDIM 768
#define E_DD 131072
#define FD 256

// ---------------------------------------------------------------------------
// Generic fp32 tiled GEMM: C[M,N] = act(A[M,K] @ W[K,N] (+ bias))
// 64x64 tile, BK=16, 256 threads, 4x4 per thread.
// ---------------------------------------------------------------------------
template <int RELU, int BIAS>
__global__ __launch_bounds__(256) void gemm_kernel(
    const float* __restrict__ A, const float* __restrict__ W,
    const float* __restrict__ bias, float* __restrict__ Cm,
    int M, int N, int K) {
  __shared__ float As[16][64];
  __shared__ float Bs[16][64];
  const int tid = threadIdx.x;
  const int tx = tid & 15, ty = tid >> 4;
  const int row0 = blockIdx.x * 64, col0 = blockIdx.y * 64;
  float acc[4][4] = {};
  const int am = tid >> 2;         // 0..63 : A row within tile
  const int ak = (tid & 3) * 4;    // 0,4,8,12 : A k within tile
  const int bk = tid >> 4;         // 0..15 : B k within tile
  const int bn = (tid & 15) * 4;   // 0..60 : B col within tile

  for (int k0 = 0; k0 < K; k0 += 16) {
#pragma unroll
    for (int i = 0; i < 4; ++i) {
      int kk = ak + i;
      int r = row0 + am, k = k0 + kk;
      float v = 0.f;
      if (r < M && k < K) v = A[(size_t)r * K + k];
      As[kk][am] = v;
    }
#pragma unroll
    for (int i = 0; i < 4; ++i) {
      int nn = bn + i;
      int k = k0 + bk, c = col0 + nn;
      float v = 0.f;
      if (k < K && c < N) v = W[(size_t)k * N + c];
      Bs[bk][nn] = v;
    }
    __syncthreads();
#pragma unroll
    for (int kk = 0; kk < 16; ++kk) {
      float a[4], b[4];
#pragma unroll
      for (int i = 0; i < 4; ++i) a[i] = As[kk][ty * 4 + i];
#pragma unroll
      for (int j = 0; j < 4; ++j) b[j] = Bs[kk][tx * 4 + j];
#pragma unroll
      for (int i = 0; i < 4; ++i)
#pragma unroll
        for (int j = 0; j < 4; ++j) acc[i][j] = fmaf(a[i], b[j], acc[i][j]);
    }
    __syncthreads();
  }
#pragma unroll
  for (int i = 0; i < 4; ++i) {
    int r = row0 + ty * 4 + i;
    if (r >= M) continue;
#pragma unroll
    for (int j = 0; j < 4; ++j) {
      int c = col0 + tx * 4 + j;
      if (c >= N) continue;
      float v = acc[i][j];
      if (BIAS) v += bias[c];
      if (RELU) v = fmaxf(v, 0.f);
      Cm[(size_t)r * N + c] = v;
    }
  }
}

// ---------------------------------------------------------------------------
// wsv[k] = sum_c W_src[k,c]*a_src[c] ; wdv[k] = sum_c W_dst[k,c]*a_dst[c]
// One block per k (256 blocks).
// ---------------------------------------------------------------------------
__global__ void wvec_kernel(const float* __restrict__ Wsrc,
                            const float* __restrict__ Wdst,
                            const float* __restrict__ a_s,
                            const float* __restrict__ a_d,
                            float* __restrict__ wsv, float* __restrict__ wdv) {
  int k = blockIdx.x;
  int t = threadIdx.x;
  __shared__ float rs[256], rd[256];
  float s = 0.f, d = 0.f;
  for (int c = t; c < CDIM; c += 256) {
    float av = a_s[c], dv = a_d[c];
    s += Wsrc[(size_t)k * CDIM + c] * av;
    d += Wdst[(size_t)k * CDIM + c] * dv;
  }
  rs[t] = s; rd[t] = d;
  __syncthreads();
  for (int st = 128; st; st >>= 1) {
    if (t < st) { rs[t] += rs[t + st]; rd[t] += rd[t + st]; }
    __syncthreads();
  }
  if (t == 0) { wsv[k] = rs[0]; wdv[k] = rd[0]; }
}

// es[i] = x[i] . wsv ; ed[i] = x[i] . wdv   (one wave per row, 4 waves/block)
__global__ void esed_kernel(const float* __restrict__ x,
                            const float* __restrict__ wsv,
                            const float* __restrict__ wdv,
                            float* __restrict__ es, float* __restrict__ ed) {
  int row = blockIdx.x * 4 + (threadIdx.x >> 6);
  int lane = threadIdx.x & 63;
  float a = 0.f, b = 0.f;
  for (int k = lane; k < FD; k += 64) {
    float v = x[(size_t)row * FD + k];
    a += v * wsv[k];
    b += v * wdv[k];
  }
  for (int off = 32; off; off >>= 1) {
    a += __shfl_down(a, off);
    b += __shfl_down(b, off);
  }
  if (lane == 0) { es[row] = a; ed[row] = b; }
}

// ---------------------------------------------------------------------------
// CSR build (dst-sorted adjacency with self loop reserved at segment head)
// ---------------------------------------------------------------------------
__global__ void count_init(int* counts) {
  int i = blockIdx.x * 256 + threadIdx.x;
  if (i < ND) counts[i] = 1;  // self loop
}
__global__ void count_edges(const int* __restrict__ dst, int* counts) {
  int e = blockIdx.x * 256 + threadIdx.x;
  if (e < E_DD) atomicAdd(&counts[dst[e]], 1);
}
__global__ void scan_kernel(const int* __restrict__ counts, int* __restrict__ offsets) {
  // single block, 512 threads x 32 contiguous each = 16384
  __shared__ int part[512];
  int t = threadIdx.x;
  int base = t * 32;
  int s = 0;
  for (int i = 0; i < 32; ++i) s += counts[base + i];
  part[t] = s;
  __syncthreads();
  if (t == 0) {
    int run = 0;
    for (int i = 0; i < 512; ++i) { int tmp = part[i]; part[i] = run; run += tmp; }
    offsets[ND] = run;
  }
  __syncthreads();
  int run = part[t];
  for (int i = 0; i < 32; ++i) { offsets[base + i] = run; run += counts[base + i]; }
}
__global__ void selfloop_init(const int* __restrict__ offsets, int* cursor, int* slots) {
  int d = blockIdx.x * 256 + threadIdx.x;
  if (d < ND) {
    int o = offsets[d];
    slots[o] = d;
    cursor[d] = o + 1;
  }
}
__global__ void scatter_edges(const int* __restrict__ src, const int* __restrict__ dst,
                              int* cursor, int* slots) {
  int e = blockIdx.x * 256 + threadIdx.x;
  if (e < E_DD) {
    int d = dst[e];
    int pos = atomicAdd(&cursor[d], 1);
    slots[pos] = src[e];
  }
}

// ---------------------------------------------------------------------------
// GAT aggregation: per dst node, softmax over incoming edges, weighted sum of
// hs rows, + bias, ReLU. One block of 256 per dst; thread owns cols t,t+256,t+512.
// ---------------------------------------------------------------------------
__global__ __launch_bounds__(256) void gat_aggregate(
    const float* __restrict__ hs, const float* __restrict__ es,
    const float* __restrict__ ed, const int* __restrict__ offsets,
    const int* __restrict__ slots, const float* __restrict__ bias,
    float* __restrict__ out) {
  int d = blockIdx.x;
  int t = threadIdx.x;
  int beg = offsets[d], end = offsets[d + 1];
  float edv = ed[d];
  __shared__ float red[256];
  // pass 1: max
  float mx = -1e30f;
  for (int j = beg + t; j < end; j += 256) {
    float e = es[slots[j]] + edv;
    e = e >= 0.f ? e : 0.2f * e;
    mx = fmaxf(mx, e);
  }
  red[t] = mx;
  __syncthreads();
  for (int st = 128; st; st >>= 1) {
    if (t < st) red[t] = fmaxf(red[t], red[t + st]);
    __syncthreads();
  }
  float m = red[0];
  __syncthreads();
  // pass 2: sum of exp
  float sm = 0.f;
  for (int j = beg + t; j < end; j += 256) {
    float e = es[slots[j]] + edv;
    e = e >= 0.f ? e : 0.2f * e;
    sm += expf(e - m);
  }
  red[t] = sm;
  __syncthreads();
  for (int st = 128; st; st >>= 1) {
    if (t < st) red[t] += red[t + st];
    __syncthreads();
  }
  float inv = 1.f / (red[0] + 1e-16f);
  __syncthreads();
  // pass 3: weighted accumulate (all threads recompute alpha; broadcast loads)
  float a0 = 0.f, a1 = 0.f, a2 = 0.f;
  for (int j = beg; j < end; ++j) {
    int srcn = slots[j];
    float e = es[srcn] + edv;
    e = e >= 0.f ? e : 0.2f * e;
    float alpha = expf(e - m) * inv;
    const float* hrow = hs + (size_t)srcn * CDIM;
    a0 = fmaf(alpha, hrow[t], a0);
    a1 = fmaf(alpha, hrow[t + 256], a1);
    a2 = fmaf(alpha, hrow[t + 512], a2);
  }
  float* orow = out + (size_t)d * CDIM;
  orow[t]       = fmaxf(a0 + bias[t], 0.f);
  orow[t + 256] = fmaxf(a1 + bias[t + 256], 0.f);
  orow[t + 512] = fmaxf(a2 + bias[t + 512], 0.f);
}

// ---------------------------------------------------------------------------
// Row-wise l2 normalize (general L), one block per row.
// ---------------------------------------------------------------------------
__global__ void l2norm_kernel(const float* __restrict__ in, float* __restrict__ out, int L) {
  int row = blockIdx.x;
  int t = threadIdx.x;
  __shared__ float red[256];
  const float* irow = in + (size_t)row * L;
  float s = 0.f;
  for (int c = t; c < L; c += 256) { float v = irow[c]; s += v * v; }
  red[t] = s;
  __syncthreads();
  for (int st = 128; st; st >>= 1) {
    if (t < st) red[t] += red[t + st];
    __syncthreads();
  }
  float inv = 1.f / fmaxf(sqrtf(red[0]), 1e-12f);
  float* orow = out + (size_t)row * L;
  for (int c = t; c < L; c += 256) orow[c] = irow[c] * inv;
}

// ---------------------------------------------------------------------------
// hidden = l2norm(concat(drug[d1], drug[d2], cell3)), rows of 3072.
// ---------------------------------------------------------------------------
__global__ __launch_bounds__(256) void hidden_build(
    const float* __restrict__ drug, const float* __restrict__ c3,
    const int* __restrict__ d1, const int* __restrict__ d2,
    float* __restrict__ hidden) {
  int row = blockIdx.x;
  int t = threadIdx.x;
  const float* s1 = drug + (size_t)d1[row] * CDIM;
  const float* s2 = drug + (size_t)d2[row] * CDIM;
  const float* s3 = c3 + (size_t)row * (2 * CDIM);
  float* hrow = hidden + (size_t)row * (4 * CDIM);
  float vals[12];
  float ss = 0.f;
#pragma unroll
  for (int i = 0; i < 12; ++i) {
    int c = t + 256 * i;
    float v;
    if (i < 3)      v = s1[c];
    else if (i < 6) v = s2[c - CDIM];
    else            v = s3[c - 2 * CDIM];
    vals[i] = v;
    ss += v * v;
  }
  __shared__ float red[256];
  red[t] = ss;
  __syncthreads();
  for (int st = 128; st; st >>= 1) {
    if (t < st) red[t] += red[t + st];
    __syncthreads();
  }
  float inv = 1.f / fmaxf(sqrtf(red[0]), 1e-12f);
#pragma unroll
  for (int i = 0; i < 12; ++i) hrow[t + 256 * i] = vals[i] * inv;
}

// Final classifier: out[row, 0:2] = h3[row] @ cls_w + cls_b. One wave per row.
__global__ void cls_kernel(const float* __restrict__ h3, const float* __restrict__ w,
                           const float* __restrict__ b, float* __restrict__ out) {
  int row = blockIdx.x * 4 + (threadIdx.x >> 6);
  int lane = threadIdx.x & 63;
  float s0 = 0.f, s1 = 0.f;
  for (int k = lane; k < CDIM; k += 64) {
    float v = h3[(size_t)row * CDIM + k];
    s0 += v * w[k * 2 + 0];
    s1 += v * w[k * 2 + 1];
  }
  for (int off = 32; off; off >>= 1) {
    s0 += __shfl_down(s0, off);
    s1 += __shfl_down(s1, off);
  }
  if (lane == 0) {
    out[row * 2 + 0] = s0 + b[0];
    out[row * 2 + 1] = s1 + b[1];
  }
}

// ---------------------------------------------------------------------------
extern "C" void kernel_launch(void* const* d_in, const int* in_sizes, int n_in,
                              void* d_out, int out_size, void* d_ws, size_t ws_size,
                              hipStream_t stream) {
  const float* x_drug   = (const float*)d_in[0];
  // d_in[1] x_target: dead (target embeddings deleted in reference)
  const float* cellf    = (const float*)d_in[2];
  const float* W_src_dd = (const float*)d_in[3];
  const float* W_dst_dd = (const float*)d_in[4];
  const float* a_src_dd = (const float*)d_in[5];
  const float* a_dst_dd = (const float*)d_in[6];
  const float* b_dd     = (const float*)d_in[7];
  // d_in[8..17]: dt/tt weights, dead
  const float* red1_w = (const float*)d_in[18];
  const float* red1_b = (const float*)d_in[19];
  const float* red2_w = (const float*)d_in[20];
  const float* red2_b = (const float*)d_in[21];
  const float* red3_w = (const float*)d_in[22];
  const float* red3_b = (const float*)d_in[23];
  const float* r2a_w  = (const float*)d_in[24];
  const float* r2a_b  = (const float*)d_in[25];
  const float* r2b_w  = (const float*)d_in[26];
  const float* r2b_b  = (const float*)d_in[27];
  const float* r2c_w  = (const float*)d_in[28];
  const float* r2c_b  = (const float*)d_in[29];
  const float* cls_w  = (const float*)d_in[30];
  const float* cls_b  = (const float*)d_in[31];
  const int* drug1_id = (const int*)d_in[32];
  const int* drug2_id = (const int*)d_in[33];
  const int* ei_dd    = (const int*)d_in[34];
  // d_in[35], d_in[36]: ei_dt, ei_tt dead
  float* out = (float*)d_out;

  const int* dd_src = ei_dd;
  const int* dd_dst = ei_dd + E_DD;

  // workspace layout
  char* w = (char*)d_ws;
  size_t off = 0;
  auto alloc = [&](size_t bytes) -> char* {
    char* p = w + off;
    off = (off + bytes + 255) & ~(size_t)255;
    return p;
  };
  float* hs     = (float*)alloc((size_t)ND * CDIM * 4);        // 50.3 MB
  float* drug   = (float*)alloc((size_t)ND * CDIM * 4);        // 50.3 MB
  float* hidden = (float*)alloc((size_t)BATCH * 4 * CDIM * 4); // 50.3 MB
  float* c1     = (float*)alloc((size_t)BATCH * 2048 * 4);     // 33.6 MB (reused as h1)
  float* c3     = (float*)alloc((size_t)BATCH * 2 * CDIM * 4); // 25.2 MB (reused as h3)
  float* celln  = (float*)alloc((size_t)BATCH * 890 * 4);      // 14.6 MB
  float* c2     = (float*)alloc((size_t)BATCH * 512 * 4);      // 8.4 MB (reused as h2)
  float* es     = (float*)alloc((size_t)ND * 4);
  float* ed     = (float*)alloc((size_t)ND * 4);
  float* wsv    = (float*)alloc(FD * 4);
  float* wdv    = (float*)alloc(FD * 4);
  int* counts   = (int*)alloc((size_t)ND * 4);
  int* offsets  = (int*)alloc((size_t)(ND + 1) * 4);
  int* cursor   = (int*)alloc((size_t)ND * 4);
  int* slots    = (int*)alloc((size_t)(E_DD + ND) * 4);
  float* h1 = c1;
  float* h2 = c2;
  float* h3 = c3;
  (void)ws_size; (void)n_in; (void)in_sizes; (void)out_size;

  // --- GAT (dd only; dt/tt are dead code) ---
  wvec_kernel<<<FD, 256, 0, stream>>>(W_src_dd, W_dst_dd, a_src_dd, a_dst_dd, wsv, wdv);
  esed_kernel<<<ND / 4, 256, 0, stream>>>(x_drug, wsv, wdv, es, ed);
  {
    dim3 g(ND / 64, CDIM / 64);
    gemm_kernel<0, 0><<<g, 256, 0, stream>>>(x_drug, W_src_dd, nullptr, hs, ND, CDIM, FD);
  }
  count_init<<<ND / 256, 256, 0, stream>>>(counts);
  count_edges<<<E_DD / 256, 256, 0, stream>>>(dd_dst, counts);
  scan_kernel<<<1, 512, 0, stream>>>(counts, offsets);
  selfloop_init<<<ND / 256, 256, 0, stream>>>(offsets, cursor, slots);
  scatter_edges<<<E_DD / 256, 256, 0, stream>>>(dd_src, dd_dst, cursor, slots);
  gat_aggregate<<<ND, 256, 0, stream>>>(hs, es, ed, offsets, slots, b_dd, drug);

  // --- cell MLP ---
  l2norm_kernel<<<BATCH, 256, 0, stream>>>(cellf, celln, 890);
  {
    dim3 g(BATCH / 64, 2048 / 64);
    gemm_kernel<1, 1><<<g, 256, 0, stream>>>(celln, red1_w, red1_b, c1, BATCH, 2048, 890);
  }
  {
    dim3 g(BATCH / 64, 512 / 64);
    gemm_kernel<1, 1><<<g, 256, 0, stream>>>(c1, red2_w, red2_b, c2, BATCH, 512, 2048);
  }
  {
    dim3 g(BATCH / 64, (2 * CDIM) / 64);
    gemm_kernel<1, 1><<<g, 256, 0, stream>>>(c2, red3_w, red3_b, c3, BATCH, 2 * CDIM, 512);
  }

  // --- fuse: gather d1,d2 + concat + l2norm ---
  hidden_build<<<BATCH, 256, 0, stream>>>(drug, c3, drug1_id, drug2_id, hidden);

  // --- head MLP ---
  {
    dim3 g(BATCH / 64, 2048 / 64);
    gemm_kernel<1, 1><<<g, 256, 0, stream>>>(hidden, r2a_w, r2a_b, h1, BATCH, 2048, 4 * CDIM);
  }
  {
    dim3 g(BATCH / 64, 512 / 64);
    gemm_kernel<1, 1><<<g, 256, 0, stream>>>(h1, r2b_w, r2b_b, h2, BATCH, 512, 2048);
  }
  {
    dim3 g(BATCH / 64, CDIM / 64);
    gemm_kernel<1, 1><<<g, 256, 0, stream>>>(h2, r2c_w, r2c_b, h3, BATCH, CDIM, 512);
  }
  cls_kernel<<<BATCH / 4, 256, 0, stream>>>(h3, cls_w, cls_b, out);
}

// Round 3
// 726.847 us; speedup vs baseline: 4.0596x; 4.0596x over previous
//
#include <hip/hip_runtime.h>
#include <cstdint>

#define ND 16384
#define BATCH 4096
#define CDIM 768
#define E_DD 131072
#define FD 256

typedef unsigned short u16;
typedef u16 u16x4 __attribute__((ext_vector_type(4)));
typedef u16 u16x8 __attribute__((ext_vector_type(8)));
typedef short s16x8 __attribute__((ext_vector_type(8)));
typedef float f32x4 __attribute__((ext_vector_type(4)));

__device__ __forceinline__ u16 f2bf(float x) {
  union { float f; uint32_t u; } v; v.f = x;
  uint32_t r = v.u + 0x7fffu + ((v.u >> 16) & 1u);
  return (u16)(r >> 16);
}
__device__ __forceinline__ float bf2f(u16 h) {
  union { float f; uint32_t u; } v; v.u = ((uint32_t)h) << 16;
  return v.f;
}
// returns (hi << 16) | lo packed; hi = bf16(x), lo = bf16(x - hi)
__device__ __forceinline__ uint32_t split2p(float x) {
  u16 h = f2bf(x);
  u16 l = f2bf(x - bf2f(h));
  return ((uint32_t)h << 16) | l;
}

// ---------------------------------------------------------------------------
// bf16x3 MFMA GEMM.  A (activations) as hi/lo bf16 [M][K]; B (weights) as
// hi/lo bf16 TRANSPOSED [N][K].  C = act(A*W + bias), W[k][n] == B[n][k].
// Block = 256 threads = 4 waves in 2x2; wave tile = (MT*16) x (NT*16).
// BM = MT*32, BN = NT*32, BK = 32 (one 16x16x32 mfma k-depth).
// LDS pitch 40 bf16 (80 B): even distribution across bank groups for
// ds_read_b128, no above-floor conflicts.
// OUT_SPLIT=1: write bf16 hi/lo (feeds next GEMM); else fp32.
// ---------------------------------------------------------------------------
#define KP 40

template <int MT, int NT, int OUT_SPLIT, int RELU, int BIAS>
__global__ __launch_bounds__(256) void mfma_gemm(
    const u16* __restrict__ Ahi, const u16* __restrict__ Alo,
    const u16* __restrict__ Bhi, const u16* __restrict__ Blo,
    const float* __restrict__ bias,
    float* __restrict__ Cf, u16* __restrict__ Chi, u16* __restrict__ Clo,
    int M, int N, int K) {
  constexpr int BM = MT * 32, BN = NT * 32;
  constexpr int ASEG = BM / 64;  // u16x8 segments per thread per A array
  constexpr int BSEG = BN / 64;
  __shared__ __align__(16) u16 As[2][BM][KP];
  __shared__ __align__(16) u16 Bs[2][BN][KP];

  const int t = threadIdx.x;
  const int bm0 = blockIdx.x * BM, bn0 = blockIdx.y * BN;
  const int wid = t >> 6, lane = t & 63;
  const int quad = lane >> 4, l16 = lane & 15;
  const int wm0 = (wid >> 1) * (MT * 16);
  const int wn0 = (wid & 1) * (NT * 16);

  f32x4 acc[MT][NT];
#pragma unroll
  for (int i = 0; i < MT; ++i)
#pragma unroll
    for (int j = 0; j < NT; ++j) acc[i][j] = (f32x4){0.f, 0.f, 0.f, 0.f};

  u16x8 pAh[ASEG], pAl[ASEG], pBh[BSEG], pBl[BSEG];

  // prefetch k0 = 0
#pragma unroll
  for (int c = 0; c < ASEG; ++c) {
    int s = t + 256 * c, row = s >> 2, kq = (s & 3) * 8;
    size_t off = (size_t)(bm0 + row) * K + kq;
    pAh[c] = *(const u16x8*)(Ahi + off);
    pAl[c] = *(const u16x8*)(Alo + off);
  }
#pragma unroll
  for (int c = 0; c < BSEG; ++c) {
    int s = t + 256 * c, row = s >> 2, kq = (s & 3) * 8;
    size_t off = (size_t)(bn0 + row) * K + kq;
    pBh[c] = *(const u16x8*)(Bhi + off);
    pBl[c] = *(const u16x8*)(Blo + off);
  }

  for (int k0 = 0;;) {
    __syncthreads();
#pragma unroll
    for (int c = 0; c < ASEG; ++c) {
      int s = t + 256 * c, row = s >> 2, kq = (s & 3) * 8;
      *(u16x8*)&As[0][row][kq] = pAh[c];
      *(u16x8*)&As[1][row][kq] = pAl[c];
    }
#pragma unroll
    for (int c = 0; c < BSEG; ++c) {
      int s = t + 256 * c, row = s >> 2, kq = (s & 3) * 8;
      *(u16x8*)&Bs[0][row][kq] = pBh[c];
      *(u16x8*)&Bs[1][row][kq] = pBl[c];
    }
    __syncthreads();

    int kn = k0 + 32;
    if (kn < K) {  // prefetch next tile while computing this one
#pragma unroll
      for (int c = 0; c < ASEG; ++c) {
        int s = t + 256 * c, row = s >> 2, kq = (s & 3) * 8;
        size_t off = (size_t)(bm0 + row) * K + kn + kq;
        pAh[c] = *(const u16x8*)(Ahi + off);
        pAl[c] = *(const u16x8*)(Alo + off);
      }
#pragma unroll
      for (int c = 0; c < BSEG; ++c) {
        int s = t + 256 * c, row = s >> 2, kq = (s & 3) * 8;
        size_t off = (size_t)(bn0 + row) * K + kn + kq;
        pBh[c] = *(const u16x8*)(Bhi + off);
        pBl[c] = *(const u16x8*)(Blo + off);
      }
    }

    s16x8 ah[MT], al[MT], bh[NT], bl[NT];
#pragma unroll
    for (int mi = 0; mi < MT; ++mi) {
      ah[mi] = *(const s16x8*)&As[0][wm0 + mi * 16 + l16][quad * 8];
      al[mi] = *(const s16x8*)&As[1][wm0 + mi * 16 + l16][quad * 8];
    }
#pragma unroll
    for (int ni = 0; ni < NT; ++ni) {
      bh[ni] = *(const s16x8*)&Bs[0][wn0 + ni * 16 + l16][quad * 8];
      bl[ni] = *(const s16x8*)&Bs[1][wn0 + ni * 16 + l16][quad * 8];
    }
#pragma unroll
    for (int mi = 0; mi < MT; ++mi)
#pragma unroll
      for (int ni = 0; ni < NT; ++ni) {
        acc[mi][ni] = __builtin_amdgcn_mfma_f32_16x16x32_bf16(
            ah[mi], bh[ni], acc[mi][ni], 0, 0, 0);
        acc[mi][ni] = __builtin_amdgcn_mfma_f32_16x16x32_bf16(
            ah[mi], bl[ni], acc[mi][ni], 0, 0, 0);
        acc[mi][ni] = __builtin_amdgcn_mfma_f32_16x16x32_bf16(
            al[mi], bh[ni], acc[mi][ni], 0, 0, 0);
      }
    k0 = kn;
    if (k0 >= K) break;
  }

  // epilogue: D row = quad*4 + reg, col = l16 (verified m89/m91 layout)
#pragma unroll
  for (int mi = 0; mi < MT; ++mi) {
#pragma unroll
    for (int ni = 0; ni < NT; ++ni) {
      int row = bm0 + wm0 + mi * 16 + quad * 4;
      int col = bn0 + wn0 + ni * 16 + l16;
      float bv = BIAS ? bias[col] : 0.f;
#pragma unroll
      for (int r = 0; r < 4; ++r) {
        float v = acc[mi][ni][r] + bv;
        if (RELU) v = fmaxf(v, 0.f);
        size_t o = (size_t)(row + r) * N + col;
        if (OUT_SPLIT) {
          uint32_t p = split2p(v);
          Chi[o] = (u16)(p >> 16);
          Clo[o] = (u16)(p & 0xffffu);
        } else {
          Cf[o] = v;
        }
      }
    }
  }
}

// ---------------------------------------------------------------------------
// Weight transpose + bf16 split: W fp32 [K][N] -> Th/Tl bf16 [N][Kpad]
// (k >= K zero-padded). Block (32,8), 32x32 tile via LDS.
// ---------------------------------------------------------------------------
__global__ void transpose_split(const float* __restrict__ W, u16* __restrict__ Th,
                                u16* __restrict__ Tl, int K, int N, int Kpad) {
  __shared__ float tile[32][33];
  int k0 = blockIdx.x * 32, n0 = blockIdx.y * 32;
  int tx = threadIdx.x, ty = threadIdx.y;
#pragma unroll
  for (int i = 0; i < 4; ++i) {
    int k = k0 + ty + 8 * i, n = n0 + tx;
    tile[ty + 8 * i][tx] = (k < K && n < N) ? W[(size_t)k * N + n] : 0.f;
  }
  __syncthreads();
#pragma unroll
  for (int i = 0; i < 4; ++i) {
    int n = n0 + ty + 8 * i, k = k0 + tx;
    if (n < N) {
      uint32_t p = split2p(tile[tx][ty + 8 * i]);
      Th[(size_t)n * Kpad + k] = (u16)(p >> 16);
      Tl[(size_t)n * Kpad + k] = (u16)(p & 0xffffu);
    }
  }
}

// Elementwise fp32 -> bf16 hi/lo split (x_drug), float4 granularity.
__global__ void split_mat(const float* __restrict__ in, u16* __restrict__ hi,
                          u16* __restrict__ lo, int n4) {
  int i = blockIdx.x * 256 + threadIdx.x;
  if (i >= n4) return;
  float4 v = ((const float4*)in)[i];
  uint32_t p0 = split2p(v.x), p1 = split2p(v.y), p2 = split2p(v.z), p3 = split2p(v.w);
  u16x4 h, l;
  h.x = (u16)(p0 >> 16); l.x = (u16)(p0 & 0xffffu);
  h.y = (u16)(p1 >> 16); l.y = (u16)(p1 & 0xffffu);
  h.z = (u16)(p2 >> 16); l.z = (u16)(p2 & 0xffffu);
  h.w = (u16)(p3 >> 16); l.w = (u16)(p3 & 0xffffu);
  *(u16x4*)&hi[i * 4] = h;
  *(u16x4*)&lo[i * 4] = l;
}

// ---------------------------------------------------------------------------
// wsv[k] = sum_c W_src[k,c]*a_src[c] ; wdv[k] = sum_c W_dst[k,c]*a_dst[c]
// ---------------------------------------------------------------------------
__global__ void wvec_kernel(const float* __restrict__ Wsrc,
                            const float* __restrict__ Wdst,
                            const float* __restrict__ a_s,
                            const float* __restrict__ a_d,
                            float* __restrict__ wsv, float* __restrict__ wdv) {
  int k = blockIdx.x;
  int t = threadIdx.x;
  __shared__ float rs[256], rd[256];
  float s = 0.f, d = 0.f;
  for (int c = t; c < CDIM; c += 256) {
    s += Wsrc[(size_t)k * CDIM + c] * a_s[c];
    d += Wdst[(size_t)k * CDIM + c] * a_d[c];
  }
  rs[t] = s; rd[t] = d;
  __syncthreads();
  for (int st = 128; st; st >>= 1) {
    if (t < st) { rs[t] += rs[t + st]; rd[t] += rd[t + st]; }
    __syncthreads();
  }
  if (t == 0) { wsv[k] = rs[0]; wdv[k] = rd[0]; }
}

__global__ void esed_kernel(const float* __restrict__ x,
                            const float* __restrict__ wsv,
                            const float* __restrict__ wdv,
                            float* __restrict__ es, float* __restrict__ ed) {
  int row = blockIdx.x * 4 + (threadIdx.x >> 6);
  int lane = threadIdx.x & 63;
  float a = 0.f, b = 0.f;
  for (int k = lane; k < FD; k += 64) {
    float v = x[(size_t)row * FD + k];
    a += v * wsv[k];
    b += v * wdv[k];
  }
  for (int off = 32; off; off >>= 1) {
    a += __shfl_down(a, off);
    b += __shfl_down(b, off);
  }
  if (lane == 0) { es[row] = a; ed[row] = b; }
}

// ---------------------------------------------------------------------------
// CSR build (dst-sorted, self loop at segment head)
// ---------------------------------------------------------------------------
__global__ void count_init(int* counts) {
  int i = blockIdx.x * 256 + threadIdx.x;
  if (i < ND) counts[i] = 1;
}
__global__ void count_edges(const int* __restrict__ dst, int* counts) {
  int e = blockIdx.x * 256 + threadIdx.x;
  if (e < E_DD) atomicAdd(&counts[dst[e]], 1);
}
__global__ void scan_kernel(const int* __restrict__ counts, int* __restrict__ offsets) {
  __shared__ int part[512];
  int t = threadIdx.x;
  int base = t * 32;
  int s = 0;
  for (int i = 0; i < 32; ++i) s += counts[base + i];
  part[t] = s;
  __syncthreads();
  if (t == 0) {
    int run = 0;
    for (int i = 0; i < 512; ++i) { int tmp = part[i]; part[i] = run; run += tmp; }
    offsets[ND] = run;
  }
  __syncthreads();
  int run = part[t];
  for (int i = 0; i < 32; ++i) { offsets[base + i] = run; run += counts[base + i]; }
}
__global__ void selfloop_init(const int* __restrict__ offsets, int* cursor, int* slots) {
  int d = blockIdx.x * 256 + threadIdx.x;
  if (d < ND) {
    int o = offsets[d];
    slots[o] = d;
    cursor[d] = o + 1;
  }
}
__global__ void scatter_edges(const int* __restrict__ src, const int* __restrict__ dst,
                              int* cursor, int* slots) {
  int e = blockIdx.x * 256 + threadIdx.x;
  if (e < E_DD) {
    int pos = atomicAdd(&cursor[dst[e]], 1);
    slots[pos] = src[e];
  }
}

// ---------------------------------------------------------------------------
// GAT aggregation (softmax over incoming edges, weighted sum of hs rows)
// ---------------------------------------------------------------------------
__global__ __launch_bounds__(256) void gat_aggregate(
    const float* __restrict__ hs, const float* __restrict__ es,
    const float* __restrict__ ed, const int* __restrict__ offsets,
    const int* __restrict__ slots, const float* __restrict__ bias,
    float* __restrict__ out) {
  int d = blockIdx.x;
  int t = threadIdx.x;
  int beg = offsets[d], end = offsets[d + 1];
  float edv = ed[d];
  __shared__ float red[256];
  float mx = -1e30f;
  for (int j = beg + t; j < end; j += 256) {
    float e = es[slots[j]] + edv;
    e = e >= 0.f ? e : 0.2f * e;
    mx = fmaxf(mx, e);
  }
  red[t] = mx;
  __syncthreads();
  for (int st = 128; st; st >>= 1) {
    if (t < st) red[t] = fmaxf(red[t], red[t + st]);
    __syncthreads();
  }
  float m = red[0];
  __syncthreads();
  float sm = 0.f;
  for (int j = beg + t; j < end; j += 256) {
    float e = es[slots[j]] + edv;
    e = e >= 0.f ? e : 0.2f * e;
    sm += expf(e - m);
  }
  red[t] = sm;
  __syncthreads();
  for (int st = 128; st; st >>= 1) {
    if (t < st) red[t] += red[t + st];
    __syncthreads();
  }
  float inv = 1.f / (red[0] + 1e-16f);
  __syncthreads();
  float a0 = 0.f, a1 = 0.f, a2 = 0.f;
  for (int j = beg; j < end; ++j) {
    int srcn = slots[j];
    float e = es[srcn] + edv;
    e = e >= 0.f ? e : 0.2f * e;
    float alpha = expf(e - m) * inv;
    const float* hrow = hs + (size_t)srcn * CDIM;
    a0 = fmaf(alpha, hrow[t], a0);
    a1 = fmaf(alpha, hrow[t + 256], a1);
    a2 = fmaf(alpha, hrow[t + 512], a2);
  }
  float* orow = out + (size_t)d * CDIM;
  orow[t]       = fmaxf(a0 + bias[t], 0.f);
  orow[t + 256] = fmaxf(a1 + bias[t + 256], 0.f);
  orow[t + 512] = fmaxf(a2 + bias[t + 512], 0.f);
}

// ---------------------------------------------------------------------------
// cell l2norm -> bf16 hi/lo [BATCH][Lp] with zero k-pad (L..Lp)
// ---------------------------------------------------------------------------
__global__ void l2norm_split(const float* __restrict__ in, u16* __restrict__ hi,
                             u16* __restrict__ lo, int L, int Lp) {
  int row = blockIdx.x;
  int t = threadIdx.x;
  __shared__ float red[256];
  const float* irow = in + (size_t)row * L;
  float s = 0.f;
  for (int c = t; c < L; c += 256) { float v = irow[c]; s += v * v; }
  red[t] = s;
  __syncthreads();
  for (int st = 128; st; st >>= 1) {
    if (t < st) red[t] += red[t + st];
    __syncthreads();
  }
  float inv = 1.f / fmaxf(sqrtf(red[0]), 1e-12f);
  for (int c = t; c < Lp; c += 256) {
    float v = (c < L) ? irow[c] * inv : 0.f;
    uint32_t p = split2p(v);
    hi[(size_t)row * Lp + c] = (u16)(p >> 16);
    lo[(size_t)row * Lp + c] = (u16)(p & 0xffffu);
  }
}

// hidden = l2norm(concat(drug[d1], drug[d2], cell3)) -> bf16 hi/lo [B][3072]
__global__ __launch_bounds__(256) void hidden_build_split(
    const float* __restrict__ drug, const float* __restrict__ c3,
    const int* __restrict__ d1, const int* __restrict__ d2,
    u16* __restrict__ hhi, u16* __restrict__ hlo) {
  int row = blockIdx.x;
  int t = threadIdx.x;
  const float* s1 = drug + (size_t)d1[row] * CDIM;
  const float* s2 = drug + (size_t)d2[row] * CDIM;
  const float* s3 = c3 + (size_t)row * (2 * CDIM);
  float vals[12];
  float ss = 0.f;
#pragma unroll
  for (int i = 0; i < 12; ++i) {
    int c = t + 256 * i;
    float v;
    if (i < 3)      v = s1[c];
    else if (i < 6) v = s2[c - CDIM];
    else            v = s3[c - 2 * CDIM];
    vals[i] = v;
    ss += v * v;
  }
  __shared__ float red[256];
  red[t] = ss;
  __syncthreads();
  for (int st = 128; st; st >>= 1) {
    if (t < st) red[t] += red[t + st];
    __syncthreads();
  }
  float inv = 1.f / fmaxf(sqrtf(red[0]), 1e-12f);
  u16* hrow_h = hhi + (size_t)row * (4 * CDIM);
  u16* hrow_l = hlo + (size_t)row * (4 * CDIM);
#pragma unroll
  for (int i = 0; i < 12; ++i) {
    uint32_t p = split2p(vals[i] * inv);
    hrow_h[t + 256 * i] = (u16)(p >> 16);
    hrow_l[t + 256 * i] = (u16)(p & 0xffffu);
  }
}

// Final classifier: out[row, 0:2] = h3[row] @ cls_w + cls_b.
__global__ void cls_kernel(const float* __restrict__ h3, const float* __restrict__ w,
                           const float* __restrict__ b, float* __restrict__ out) {
  int row = blockIdx.x * 4 + (threadIdx.x >> 6);
  int lane = threadIdx.x & 63;
  float s0 = 0.f, s1 = 0.f;
  for (int k = lane; k < CDIM; k += 64) {
    float v = h3[(size_t)row * CDIM + k];
    s0 += v * w[k * 2 + 0];
    s1 += v * w[k * 2 + 1];
  }
  for (int off = 32; off; off >>= 1) {
    s0 += __shfl_down(s0, off);
    s1 += __shfl_down(s1, off);
  }
  if (lane == 0) {
    out[row * 2 + 0] = s0 + b[0];
    out[row * 2 + 1] = s1 + b[1];
  }
}

// ---------------------------------------------------------------------------
extern "C" void kernel_launch(void* const* d_in, const int* in_sizes, int n_in,
                              void* d_out, int out_size, void* d_ws, size_t ws_size,
                              hipStream_t stream) {
  const float* x_drug   = (const float*)d_in[0];
  const float* cellf    = (const float*)d_in[2];
  const float* W_src_dd = (const float*)d_in[3];
  const float* W_dst_dd = (const float*)d_in[4];
  const float* a_src_dd = (const float*)d_in[5];
  const float* a_dst_dd = (const float*)d_in[6];
  const float* b_dd     = (const float*)d_in[7];
  const float* red1_w = (const float*)d_in[18];
  const float* red1_b = (const float*)d_in[19];
  const float* red2_w = (const float*)d_in[20];
  const float* red2_b = (const float*)d_in[21];
  const float* red3_w = (const float*)d_in[22];
  const float* red3_b = (const float*)d_in[23];
  const float* r2a_w  = (const float*)d_in[24];
  const float* r2a_b  = (const float*)d_in[25];
  const float* r2b_w  = (const float*)d_in[26];
  const float* r2b_b  = (const float*)d_in[27];
  const float* r2c_w  = (const float*)d_in[28];
  const float* r2c_b  = (const float*)d_in[29];
  const float* cls_w  = (const float*)d_in[30];
  const float* cls_b  = (const float*)d_in[31];
  const int* drug1_id = (const int*)d_in[32];
  const int* drug2_id = (const int*)d_in[33];
  const int* ei_dd    = (const int*)d_in[34];
  float* out = (float*)d_out;

  const int* dd_src = ei_dd;
  const int* dd_dst = ei_dd + E_DD;

  char* w = (char*)d_ws;
  size_t off = 0;
  auto alloc = [&](size_t bytes) -> char* {
    char* p = w + off;
    off = (off + bytes + 255) & ~(size_t)255;
    return p;
  };
  // fp32 buffers
  float* hs   = (float*)alloc((size_t)ND * CDIM * 4);       // 50.3 MB; reused as hidden hi/lo
  float* drug = (float*)alloc((size_t)ND * CDIM * 4);       // 50.3 MB
  float* c3   = (float*)alloc((size_t)BATCH * 2 * CDIM * 4);// 25.2 MB; reused as h3
  float* h3 = c3;
  u16* hid_hi = (u16*)hs;                                   // alias (hs dead after GAT)
  u16* hid_lo = hid_hi + (size_t)BATCH * 4 * CDIM;
  // activation splits
  u16* xd_hi = (u16*)alloc((size_t)ND * FD * 2);
  u16* xd_lo = (u16*)alloc((size_t)ND * FD * 2);
  u16* cn_hi = (u16*)alloc((size_t)BATCH * 896 * 2);
  u16* cn_lo = (u16*)alloc((size_t)BATCH * 896 * 2);
  u16* c1_hi = (u16*)alloc((size_t)BATCH * 2048 * 2);       // shared with h1
  u16* c1_lo = (u16*)alloc((size_t)BATCH * 2048 * 2);
  u16* c2_hi = (u16*)alloc((size_t)BATCH * 512 * 2);        // shared with h2
  u16* c2_lo = (u16*)alloc((size_t)BATCH * 512 * 2);
  // transposed+split weights [N][Kpad]
  u16* wsrcT_hi = (u16*)alloc((size_t)CDIM * FD * 2);
  u16* wsrcT_lo = (u16*)alloc((size_t)CDIM * FD * 2);
  u16* r1T_hi = (u16*)alloc((size_t)2048 * 896 * 2);
  u16* r1T_lo = (u16*)alloc((size_t)2048 * 896 * 2);
  u16* r2T_hi = (u16*)alloc((size_t)512 * 2048 * 2);
  u16* r2T_lo = (u16*)alloc((size_t)512 * 2048 * 2);
  u16* r3T_hi = (u16*)alloc((size_t)1536 * 512 * 2);
  u16* r3T_lo = (u16*)alloc((size_t)1536 * 512 * 2);
  u16* raT_hi = (u16*)alloc((size_t)2048 * 3072 * 2);
  u16* raT_lo = (u16*)alloc((size_t)2048 * 3072 * 2);
  u16* rbT_hi = (u16*)alloc((size_t)512 * 2048 * 2);
  u16* rbT_lo = (u16*)alloc((size_t)512 * 2048 * 2);
  u16* rcT_hi = (u16*)alloc((size_t)768 * 512 * 2);
  u16* rcT_lo = (u16*)alloc((size_t)768 * 512 * 2);
  // GAT scalars / CSR
  float* es  = (float*)alloc((size_t)ND * 4);
  float* ed  = (float*)alloc((size_t)ND * 4);
  float* wsv = (float*)alloc(FD * 4);
  float* wdv = (float*)alloc(FD * 4);
  int* counts  = (int*)alloc((size_t)ND * 4);
  int* offsets = (int*)alloc((size_t)(ND + 1) * 4);
  int* cursor  = (int*)alloc((size_t)ND * 4);
  int* slots   = (int*)alloc((size_t)(E_DD + ND) * 4);
  (void)ws_size; (void)n_in; (void)in_sizes; (void)out_size;

  dim3 tb(32, 8);
  // weight transposes+splits: W [K][N] -> [N][Kpad]
  transpose_split<<<dim3(FD / 32, CDIM / 32), tb, 0, stream>>>(W_src_dd, wsrcT_hi, wsrcT_lo, FD, CDIM, FD);
  transpose_split<<<dim3(896 / 32, 2048 / 32), tb, 0, stream>>>(red1_w, r1T_hi, r1T_lo, 890, 2048, 896);
  transpose_split<<<dim3(2048 / 32, 512 / 32), tb, 0, stream>>>(red2_w, r2T_hi, r2T_lo, 2048, 512, 2048);
  transpose_split<<<dim3(512 / 32, 1536 / 32), tb, 0, stream>>>(red3_w, r3T_hi, r3T_lo, 512, 1536, 512);
  transpose_split<<<dim3(3072 / 32, 2048 / 32), tb, 0, stream>>>(r2a_w, raT_hi, raT_lo, 3072, 2048, 3072);
  transpose_split<<<dim3(2048 / 32, 512 / 32), tb, 0, stream>>>(r2b_w, rbT_hi, rbT_lo, 2048, 512, 2048);
  transpose_split<<<dim3(512 / 32, 768 / 32), tb, 0, stream>>>(r2c_w, rcT_hi, rcT_lo, 512, 768, 512);
  split_mat<<<(ND * FD / 4 + 255) / 256, 256, 0, stream>>>(x_drug, xd_hi, xd_lo, ND * FD / 4);

  // --- GAT (dd only; dt/tt dead) ---
  wvec_kernel<<<FD, 256, 0, stream>>>(W_src_dd, W_dst_dd, a_src_dd, a_dst_dd, wsv, wdv);
  esed_kernel<<<ND / 4, 256, 0, stream>>>(x_drug, wsv, wdv, es, ed);
  mfma_gemm<4, 4, 0, 0, 0><<<dim3(ND / 128, CDIM / 128), 256, 0, stream>>>(
      xd_hi, xd_lo, wsrcT_hi, wsrcT_lo, nullptr, hs, nullptr, nullptr, ND, CDIM, FD);
  count_init<<<ND / 256, 256, 0, stream>>>(counts);
  count_edges<<<E_DD / 256, 256, 0, stream>>>(dd_dst, counts);
  scan_kernel<<<1, 512, 0, stream>>>(counts, offsets);
  selfloop_init<<<ND / 256, 256, 0, stream>>>(offsets, cursor, slots);
  scatter_edges<<<E_DD / 256, 256, 0, stream>>>(dd_src, dd_dst, cursor, slots);
  gat_aggregate<<<ND, 256, 0, stream>>>(hs, es, ed, offsets, slots, b_dd, drug);

  // --- cell MLP ---
  l2norm_split<<<BATCH, 256, 0, stream>>>(cellf, cn_hi, cn_lo, 890, 896);
  mfma_gemm<4, 4, 1, 1, 1><<<dim3(BATCH / 128, 2048 / 128), 256, 0, stream>>>(
      cn_hi, cn_lo, r1T_hi, r1T_lo, red1_b, nullptr, c1_hi, c1_lo, BATCH, 2048, 896);
  mfma_gemm<2, 2, 1, 1, 1><<<dim3(BATCH / 64, 512 / 64), 256, 0, stream>>>(
      c1_hi, c1_lo, r2T_hi, r2T_lo, red2_b, nullptr, c2_hi, c2_lo, BATCH, 512, 2048);
  mfma_gemm<4, 4, 0, 1, 1><<<dim3(BATCH / 128, 1536 / 128), 256, 0, stream>>>(
      c2_hi, c2_lo, r3T_hi, r3T_lo, red3_b, c3, nullptr, nullptr, BATCH, 1536, 512);

  // --- gather + concat + l2norm -> split (hidden aliases hs) ---
  hidden_build_split<<<BATCH, 256, 0, stream>>>(drug, c3, drug1_id, drug2_id, hid_hi, hid_lo);

  // --- head MLP (h1/h2 alias c1/c2, h3 aliases c3) ---
  mfma_gemm<4, 4, 1, 1, 1><<<dim3(BATCH / 128, 2048 / 128), 256, 0, stream>>>(
      hid_hi, hid_lo, raT_hi, raT_lo, r2a_b, nullptr, c1_hi, c1_lo, BATCH, 2048, 3072);
  mfma_gemm<2, 2, 1, 1, 1><<<dim3(BATCH / 64, 512 / 64), 256, 0, stream>>>(
      c1_hi, c1_lo, rbT_hi, rbT_lo, r2b_b, nullptr, c2_hi, c2_lo, BATCH, 512, 2048);
  mfma_gemm<2, 2, 0, 1, 1><<<dim3(BATCH / 64, CDIM / 64), 256, 0, stream>>>(
      c2_hi, c2_lo, rcT_hi, rcT_lo, r2c_b, h3, nullptr, nullptr, BATCH, CDIM, 512);
  cls_kernel<<<BATCH / 4, 256, 0, stream>>>(h3, cls_w, cls_b, out);
}

// Round 5
// 702.418 us; speedup vs baseline: 4.2008x; 1.0348x over previous
//
#include <hip/hip_runtime.h>
#include <cstdint>

#define ND 16384
#define BATCH 4096
#define CDIM 768
#define E_DD 131072
#define FD 256

typedef unsigned short u16;
typedef u16 u16x4 __attribute__((ext_vector_type(4)));
typedef u16 u16x8 __attribute__((ext_vector_type(8)));
typedef short s16x8 __attribute__((ext_vector_type(8)));
typedef float f32x4 __attribute__((ext_vector_type(4)));

__device__ __forceinline__ u16 f2bf(float x) {
  union { float f; uint32_t u; } v; v.f = x;
  uint32_t r = v.u + 0x7fffu + ((v.u >> 16) & 1u);
  return (u16)(r >> 16);
}
__device__ __forceinline__ float bf2f(u16 h) {
  union { float f; uint32_t u; } v; v.u = ((uint32_t)h) << 16;
  return v.f;
}
// (hi << 16) | lo ; hi = bf16(x), lo = bf16(x - hi)
__device__ __forceinline__ uint32_t split2p(float x) {
  u16 h = f2bf(x);
  u16 l = f2bf(x - bf2f(h));
  return ((uint32_t)h << 16) | l;
}

// ---------------------------------------------------------------------------
// bf16x3 MFMA GEMM, 128x128 tile, BK=32, 4 waves (2x2), MT=NT=4.
// A hi/lo [M][K]; B hi/lo transposed [N][K].
// KS>1: split-K partial mode — blockIdx.z selects K-chunk, writes fp32
// partial at Cf + z*M*N, no bias/relu/split.
// ---------------------------------------------------------------------------
#define KP 40

template <int KS, int OUT_SPLIT, int RELU, int BIAS>
__global__ __launch_bounds__(256) void mfma_gemm(
    const u16* __restrict__ Ahi, const u16* __restrict__ Alo,
    const u16* __restrict__ Bhi, const u16* __restrict__ Blo,
    const float* __restrict__ bias,
    float* __restrict__ Cf, u16* __restrict__ Chi, u16* __restrict__ Clo,
    int M, int N, int K) {
  constexpr int MT = 4, NT = 4;
  constexpr int BM = 128, BN = 128;
  constexpr int ASEG = BM / 64;
  constexpr int BSEG = BN / 64;
  __shared__ __align__(16) u16 As[2][BM][KP];
  __shared__ __align__(16) u16 Bs[2][BN][KP];

  const int t = threadIdx.x;
  const int bm0 = blockIdx.x * BM, bn0 = blockIdx.y * BN;
  const int wid = t >> 6, lane = t & 63;
  const int quad = lane >> 4, l16 = lane & 15;
  const int wm0 = (wid >> 1) * (MT * 16);
  const int wn0 = (wid & 1) * (NT * 16);

  const int chunk = K / KS;
  const int kbeg = (KS > 1) ? (int)blockIdx.z * chunk : 0;
  const int kend = kbeg + chunk;

  f32x4 acc[MT][NT];
#pragma unroll
  for (int i = 0; i < MT; ++i)
#pragma unroll
    for (int j = 0; j < NT; ++j) acc[i][j] = (f32x4){0.f, 0.f, 0.f, 0.f};

  u16x8 pAh[ASEG], pAl[ASEG], pBh[BSEG], pBl[BSEG];

#pragma unroll
  for (int c = 0; c < ASEG; ++c) {
    int s = t + 256 * c, row = s >> 2, kq = (s & 3) * 8;
    size_t off = (size_t)(bm0 + row) * K + kbeg + kq;
    pAh[c] = *(const u16x8*)(Ahi + off);
    pAl[c] = *(const u16x8*)(Alo + off);
  }
#pragma unroll
  for (int c = 0; c < BSEG; ++c) {
    int s = t + 256 * c, row = s >> 2, kq = (s & 3) * 8;
    size_t off = (size_t)(bn0 + row) * K + kbeg + kq;
    pBh[c] = *(const u16x8*)(Bhi + off);
    pBl[c] = *(const u16x8*)(Blo + off);
  }

  for (int k0 = kbeg;;) {
    __syncthreads();
#pragma unroll
    for (int c = 0; c < ASEG; ++c) {
      int s = t + 256 * c, row = s >> 2, kq = (s & 3) * 8;
      *(u16x8*)&As[0][row][kq] = pAh[c];
      *(u16x8*)&As[1][row][kq] = pAl[c];
    }
#pragma unroll
    for (int c = 0; c < BSEG; ++c) {
      int s = t + 256 * c, row = s >> 2, kq = (s & 3) * 8;
      *(u16x8*)&Bs[0][row][kq] = pBh[c];
      *(u16x8*)&Bs[1][row][kq] = pBl[c];
    }
    __syncthreads();

    int kn = k0 + 32;
    if (kn < kend) {
#pragma unroll
      for (int c = 0; c < ASEG; ++c) {
        int s = t + 256 * c, row = s >> 2, kq = (s & 3) * 8;
        size_t off = (size_t)(bm0 + row) * K + kn + kq;
        pAh[c] = *(const u16x8*)(Ahi + off);
        pAl[c] = *(const u16x8*)(Alo + off);
      }
#pragma unroll
      for (int c = 0; c < BSEG; ++c) {
        int s = t + 256 * c, row = s >> 2, kq = (s & 3) * 8;
        size_t off = (size_t)(bn0 + row) * K + kn + kq;
        pBh[c] = *(const u16x8*)(Bhi + off);
        pBl[c] = *(const u16x8*)(Blo + off);
      }
    }

    s16x8 ah[MT], al[MT], bh[NT], bl[NT];
#pragma unroll
    for (int mi = 0; mi < MT; ++mi) {
      ah[mi] = *(const s16x8*)&As[0][wm0 + mi * 16 + l16][quad * 8];
      al[mi] = *(const s16x8*)&As[1][wm0 + mi * 16 + l16][quad * 8];
    }
#pragma unroll
    for (int ni = 0; ni < NT; ++ni) {
      bh[ni] = *(const s16x8*)&Bs[0][wn0 + ni * 16 + l16][quad * 8];
      bl[ni] = *(const s16x8*)&Bs[1][wn0 + ni * 16 + l16][quad * 8];
    }
#pragma unroll
    for (int mi = 0; mi < MT; ++mi)
#pragma unroll
      for (int ni = 0; ni < NT; ++ni) {
        acc[mi][ni] = __builtin_amdgcn_mfma_f32_16x16x32_bf16(
            ah[mi], bh[ni], acc[mi][ni], 0, 0, 0);
        acc[mi][ni] = __builtin_amdgcn_mfma_f32_16x16x32_bf16(
            ah[mi], bl[ni], acc[mi][ni], 0, 0, 0);
        acc[mi][ni] = __builtin_amdgcn_mfma_f32_16x16x32_bf16(
            al[mi], bh[ni], acc[mi][ni], 0, 0, 0);
      }
    k0 = kn;
    if (k0 >= kend) break;
  }

  // D row = quad*4 + reg, col = l16 (m89/m91 layout)
  float* Cp = (KS > 1) ? Cf + (size_t)blockIdx.z * M * N : Cf;
#pragma unroll
  for (int mi = 0; mi < MT; ++mi) {
#pragma unroll
    for (int ni = 0; ni < NT; ++ni) {
      int row = bm0 + wm0 + mi * 16 + quad * 4;
      int col = bn0 + wn0 + ni * 16 + l16;
      float bv = BIAS ? bias[col] : 0.f;
#pragma unroll
      for (int r = 0; r < 4; ++r) {
        float v = acc[mi][ni][r] + bv;
        if (RELU) v = fmaxf(v, 0.f);
        size_t o = (size_t)(row + r) * N + col;
        if (OUT_SPLIT) {
          uint32_t p = split2p(v);
          Chi[o] = (u16)(p >> 16);
          Clo[o] = (u16)(p & 0xffffu);
        } else {
          Cp[o] = v;
        }
      }
    }
  }
}

// ---------------------------------------------------------------------------
// Split-K reduce: sum KS fp32 partials, +bias, relu, bf16 hi/lo split.
// ---------------------------------------------------------------------------
template <int KS>
__global__ void reduce_split_ks(const float* __restrict__ P,
                                const float* __restrict__ bias,
                                u16* __restrict__ Chi, u16* __restrict__ Clo,
                                int M, int N) {
  int i = blockIdx.x * 256 + threadIdx.x;
  int total = (M * N) >> 2;
  if (i >= total) return;
  f32x4 s = ((const f32x4*)P)[i];
#pragma unroll
  for (int z = 1; z < KS; ++z) s += ((const f32x4*)P)[(size_t)z * total + i];
  int col = (i * 4) % N;
  f32x4 bv = *(const f32x4*)(bias + col);
  u16x4 h, l;
#pragma unroll
  for (int e = 0; e < 4; ++e) {
    float v = fmaxf(s[e] + bv[e], 0.f);
    uint32_t p = split2p(v);
    h[e] = (u16)(p >> 16);
    l[e] = (u16)(p & 0xffffu);
  }
  *(u16x4*)&Chi[i * 4] = h;
  *(u16x4*)&Clo[i * 4] = l;
}

// ---------------------------------------------------------------------------
// r2c reduce fused with classifier: h = relu(P0+P1+bias) per row (768),
// out[row] = h @ cls_w + cls_b. One wave per row.
// ---------------------------------------------------------------------------
__global__ void reduce_cls(const float* __restrict__ P,
                           const float* __restrict__ bias,
                           const float* __restrict__ clsw,
                           const float* __restrict__ clsb,
                           float* __restrict__ out) {
  int row = blockIdx.x * 4 + (threadIdx.x >> 6);
  int lane = threadIdx.x & 63;
  const f32x4* p0 = (const f32x4*)(P + (size_t)row * CDIM);
  const f32x4* p1 = (const f32x4*)(P + (size_t)BATCH * CDIM + (size_t)row * CDIM);
  float s0 = 0.f, s1 = 0.f;
#pragma unroll
  for (int i = 0; i < 3; ++i) {
    int c4 = lane + 64 * i;
    f32x4 a = p0[c4] + p1[c4];
    f32x4 bv = *(const f32x4*)(bias + c4 * 4);
#pragma unroll
    for (int e = 0; e < 4; ++e) {
      float h = fmaxf(a[e] + bv[e], 0.f);
      int c = c4 * 4 + e;
      s0 = fmaf(h, clsw[c * 2 + 0], s0);
      s1 = fmaf(h, clsw[c * 2 + 1], s1);
    }
  }
#pragma unroll
  for (int m = 32; m; m >>= 1) {
    s0 += __shfl_xor(s0, m);
    s1 += __shfl_xor(s1, m);
  }
  if (lane == 0) {
    out[row * 2 + 0] = s0 + clsb[0];
    out[row * 2 + 1] = s1 + clsb[1];
  }
}

// ---------------------------------------------------------------------------
// Multi-matrix weight transpose + bf16 split: W fp32 [K][N] -> [N][Kpad].
// ---------------------------------------------------------------------------
struct TDesc {
  const float* W;
  u16* Th;
  u16* Tl;
  int K, N, Kpad, start;
};
struct TPack { TDesc d[7]; };

__global__ void multi_transpose(TPack p) {
  __shared__ float tile[32][33];
  int b = blockIdx.x;
  int mi = 0;
#pragma unroll
  for (int i = 1; i < 7; ++i)
    if (b >= p.d[i].start) mi = i;
  TDesc dd = p.d[mi];
  int rel = b - dd.start;
  int tilesX = dd.Kpad / 32;
  int k0 = (rel % tilesX) * 32, n0 = (rel / tilesX) * 32;
  int tx = threadIdx.x, ty = threadIdx.y;
#pragma unroll
  for (int i = 0; i < 4; ++i) {
    int k = k0 + ty + 8 * i, n = n0 + tx;
    tile[ty + 8 * i][tx] = (k < dd.K && n < dd.N) ? dd.W[(size_t)k * dd.N + n] : 0.f;
  }
  __syncthreads();
#pragma unroll
  for (int i = 0; i < 4; ++i) {
    int n = n0 + ty + 8 * i, k = k0 + tx;
    if (n < dd.N) {
      uint32_t pk = split2p(tile[tx][ty + 8 * i]);
      dd.Th[(size_t)n * dd.Kpad + k] = (u16)(pk >> 16);
      dd.Tl[(size_t)n * dd.Kpad + k] = (u16)(pk & 0xffffu);
    }
  }
}

// ---------------------------------------------------------------------------
// wsv[k] = sum_c W_src[k,c]*a_src[c] ; wdv[k] = sum_c W_dst[k,c]*a_dst[c]
// ---------------------------------------------------------------------------
__global__ void wvec_kernel(const float* __restrict__ Wsrc,
                            const float* __restrict__ Wdst,
                            const float* __restrict__ a_s,
                            const float* __restrict__ a_d,
                            float* __restrict__ wsv, float* __restrict__ wdv) {
  int k = blockIdx.x;
  int t = threadIdx.x;
  __shared__ float rs[256], rd[256];
  float s = 0.f, d = 0.f;
  for (int c = t; c < CDIM; c += 256) {
    s += Wsrc[(size_t)k * CDIM + c] * a_s[c];
    d += Wdst[(size_t)k * CDIM + c] * a_d[c];
  }
  rs[t] = s; rd[t] = d;
  __syncthreads();
  for (int st = 128; st; st >>= 1) {
    if (t < st) { rs[t] += rs[t + st]; rd[t] += rd[t + st]; }
    __syncthreads();
  }
  if (t == 0) { wsv[k] = rs[0]; wdv[k] = rd[0]; }
}

// ---------------------------------------------------------------------------
// Fused: x_drug bf16 hi/lo split + es/ed row dots. One wave per row.
// ---------------------------------------------------------------------------
__global__ void split_esed(const float* __restrict__ x,
                           const float* __restrict__ wsv,
                           const float* __restrict__ wdv,
                           u16* __restrict__ hi, u16* __restrict__ lo,
                           float* __restrict__ es, float* __restrict__ ed) {
  int i = blockIdx.x * 256 + threadIdx.x;  // float4 index
  int lane = threadIdx.x & 63;
  int row = i >> 6;
  int c4 = lane * 4;
  f32x4 v = ((const f32x4*)x)[i];
  u16x4 h, l;
#pragma unroll
  for (int e = 0; e < 4; ++e) {
    uint32_t p = split2p(v[e]);
    h[e] = (u16)(p >> 16);
    l[e] = (u16)(p & 0xffffu);
  }
  *(u16x4*)&hi[i * 4] = h;
  *(u16x4*)&lo[i * 4] = l;
  f32x4 ws = *(const f32x4*)(wsv + c4);
  f32x4 wd = *(const f32x4*)(wdv + c4);
  float a = v[0] * ws[0] + v[1] * ws[1] + v[2] * ws[2] + v[3] * ws[3];
  float b = v[0] * wd[0] + v[1] * wd[1] + v[2] * wd[2] + v[3] * wd[3];
#pragma unroll
  for (int m = 32; m; m >>= 1) {
    a += __shfl_xor(a, m);
    b += __shfl_xor(b, m);
  }
  if (lane == 0) { es[row] = a; ed[row] = b; }
}

// ---------------------------------------------------------------------------
// CSR build (dst-sorted, self loop at segment head)
// ---------------------------------------------------------------------------
__global__ void count_init(int* counts) {
  int i = blockIdx.x * 256 + threadIdx.x;
  if (i < ND) counts[i] = 1;
}
__global__ void count_edges(const int* __restrict__ dst, int* counts) {
  int e = blockIdx.x * 256 + threadIdx.x;
  if (e < E_DD) atomicAdd(&counts[dst[e]], 1);
}
__global__ void scan_kernel(const int* __restrict__ counts, int* __restrict__ offsets) {
  __shared__ int part[512];
  int t = threadIdx.x;
  int base = t * 32;
  int s = 0;
  for (int i = 0; i < 32; ++i) s += counts[base + i];
  part[t] = s;
  __syncthreads();
  if (t == 0) {
    int run = 0;
    for (int i = 0; i < 512; ++i) { int tmp = part[i]; part[i] = run; run += tmp; }
    offsets[ND] = run;
  }
  __syncthreads();
  int run = part[t];
  for (int i = 0; i < 32; ++i) { offsets[base + i] = run; run += counts[base + i]; }
}
__global__ void selfloop_init(const int* __restrict__ offsets, int* cursor, int* slots) {
  int d = blockIdx.x * 256 + threadIdx.x;
  if (d < ND) {
    int o = offsets[d];
    slots[o] = d;
    cursor[d] = o + 1;
  }
}
__global__ void scatter_edges(const int* __restrict__ src, const int* __restrict__ dst,
                              int* cursor, int* slots) {
  int e = blockIdx.x * 256 + threadIdx.x;
  if (e < E_DD) {
    int pos = atomicAdd(&cursor[dst[e]], 1);
    slots[pos] = src[e];
  }
}

// ---------------------------------------------------------------------------
// GAT aggregation: ONE WAVE per dst node (deg~9). Shuffle reductions,
// float4 column loads (768 = 64 lanes x 3 x float4).
// ---------------------------------------------------------------------------
__global__ __launch_bounds__(256) void gat_aggregate(
    const float* __restrict__ hs, const float* __restrict__ es,
    const float* __restrict__ ed, const int* __restrict__ offsets,
    const int* __restrict__ slots, const float* __restrict__ bias,
    float* __restrict__ out) {
  int d = blockIdx.x * 4 + (threadIdx.x >> 6);
  int lane = threadIdx.x & 63;
  int beg = offsets[d], end = offsets[d + 1];
  float edv = ed[d];
  float mx = -1e30f;
  for (int j = beg + lane; j < end; j += 64) {
    float e = es[slots[j]] + edv;
    e = e >= 0.f ? e : 0.2f * e;
    mx = fmaxf(mx, e);
  }
#pragma unroll
  for (int m = 32; m; m >>= 1) mx = fmaxf(mx, __shfl_xor(mx, m));
  float sm = 0.f;
  for (int j = beg + lane; j < end; j += 64) {
    float e = es[slots[j]] + edv;
    e = e >= 0.f ? e : 0.2f * e;
    sm += expf(e - mx);
  }
#pragma unroll
  for (int m = 32; m; m >>= 1) sm += __shfl_xor(sm, m);
  float inv = 1.f / (sm + 1e-16f);
  f32x4 a0 = {0.f, 0.f, 0.f, 0.f}, a1 = a0, a2 = a0;
  for (int j = beg; j < end; ++j) {
    int srcn = slots[j];
    float e = es[srcn] + edv;
    e = e >= 0.f ? e : 0.2f * e;
    float alpha = expf(e - mx) * inv;
    const f32x4* hrow = (const f32x4*)(hs + (size_t)srcn * CDIM);
    a0 += alpha * hrow[lane];
    a1 += alpha * hrow[lane + 64];
    a2 += alpha * hrow[lane + 128];
  }
  float* orow = out + (size_t)d * CDIM;
  const f32x4* bv = (const f32x4*)bias;
  f32x4 b0 = bv[lane], b1 = bv[lane + 64], b2 = bv[lane + 128];
  f32x4 o0, o1, o2;
#pragma unroll
  for (int e = 0; e < 4; ++e) {
    o0[e] = fmaxf(a0[e] + b0[e], 0.f);
    o1[e] = fmaxf(a1[e] + b1[e], 0.f);
    o2[e] = fmaxf(a2[e] + b2[e], 0.f);
  }
  ((f32x4*)orow)[lane] = o0;
  ((f32x4*)orow)[lane + 64] = o1;
  ((f32x4*)orow)[lane + 128] = o2;
}

// ---------------------------------------------------------------------------
// cell l2norm -> bf16 hi/lo [BATCH][Lp], zero pad L..Lp
// ---------------------------------------------------------------------------
__global__ void l2norm_split(const float* __restrict__ in, u16* __restrict__ hi,
                             u16* __restrict__ lo, int L, int Lp) {
  int row = blockIdx.x;
  int t = threadIdx.x;
  __shared__ float red[256];
  const float* irow = in + (size_t)row * L;
  float s = 0.f;
  for (int c = t; c < L; c += 256) { float v = irow[c]; s += v * v; }
  red[t] = s;
  __syncthreads();
  for (int st = 128; st; st >>= 1) {
    if (t < st) red[t] += red[t + st];
    __syncthreads();
  }
  float inv = 1.f / fmaxf(sqrtf(red[0]), 1e-12f);
  for (int c = t; c < Lp; c += 256) {
    float v = (c < L) ? irow[c] * inv : 0.f;
    uint32_t p = split2p(v);
    hi[(size_t)row * Lp + c] = (u16)(p >> 16);
    lo[(size_t)row * Lp + c] = (u16)(p & 0xffffu);
  }
}

// hidden = l2norm(concat(drug[d1], drug[d2], cell3)) -> bf16 hi/lo [B][3072]
__global__ __launch_bounds__(256) void hidden_build_split(
    const float* __restrict__ drug, const float* __restrict__ c3,
    const int* __restrict__ d1, const int* __restrict__ d2,
    u16* __restrict__ hhi, u16* __restrict__ hlo) {
  int row = blockIdx.x;
  int t = threadIdx.x;
  const float* s1 = drug + (size_t)d1[row] * CDIM;
  const float* s2 = drug + (size_t)d2[row] * CDIM;
  const float* s3 = c3 + (size_t)row * (2 * CDIM);
  float vals[12];
  float ss = 0.f;
#pragma unroll
  for (int i = 0; i < 12; ++i) {
    int c = t + 256 * i;
    float v;
    if (i < 3)      v = s1[c];
    else if (i < 6) v = s2[c - CDIM];
    else            v = s3[c - 2 * CDIM];
    vals[i] = v;
    ss += v * v;
  }
  __shared__ float red[256];
  red[t] = ss;
  __syncthreads();
  for (int st = 128; st; st >>= 1) {
    if (t < st) red[t] += red[t + st];
    __syncthreads();
  }
  float inv = 1.f / fmaxf(sqrtf(red[0]), 1e-12f);
  u16* hrow_h = hhi + (size_t)row * (4 * CDIM);
  u16* hrow_l = hlo + (size_t)row * (4 * CDIM);
#pragma unroll
  for (int i = 0; i < 12; ++i) {
    uint32_t p = split2p(vals[i] * inv);
    hrow_h[t + 256 * i] = (u16)(p >> 16);
    hrow_l[t + 256 * i] = (u16)(p & 0xffffu);
  }
}

// ---------------------------------------------------------------------------
extern "C" void kernel_launch(void* const* d_in, const int* in_sizes, int n_in,
                              void* d_out, int out_size, void* d_ws, size_t ws_size,
                              hipStream_t stream) {
  const float* x_drug   = (const float*)d_in[0];
  const float* cellf    = (const float*)d_in[2];
  const float* W_src_dd = (const float*)d_in[3];
  const float* W_dst_dd = (const float*)d_in[4];
  const float* a_src_dd = (const float*)d_in[5];
  const float* a_dst_dd = (const float*)d_in[6];
  const float* b_dd     = (const float*)d_in[7];
  const float* red1_w = (const float*)d_in[18];
  const float* red1_b = (const float*)d_in[19];
  const float* red2_w = (const float*)d_in[20];
  const float* red2_b = (const float*)d_in[21];
  const float* red3_w = (const float*)d_in[22];
  const float* red3_b = (const float*)d_in[23];
  const float* r2a_w  = (const float*)d_in[24];
  const float* r2a_b  = (const float*)d_in[25];
  const float* r2b_w  = (const float*)d_in[26];
  const float* r2b_b  = (const float*)d_in[27];
  const float* r2c_w  = (const float*)d_in[28];
  const float* r2c_b  = (const float*)d_in[29];
  const float* cls_w  = (const float*)d_in[30];
  const float* cls_b  = (const float*)d_in[31];
  const int* drug1_id = (const int*)d_in[32];
  const int* drug2_id = (const int*)d_in[33];
  const int* ei_dd    = (const int*)d_in[34];
  float* out = (float*)d_out;

  const int* dd_src = ei_dd;
  const int* dd_dst = ei_dd + E_DD;

  char* w = (char*)d_ws;
  size_t off = 0;
  auto alloc = [&](size_t bytes) -> char* {
    char* p = w + off;
    off = (off + bytes + 255) & ~(size_t)255;
    return p;
  };
  // fp32 buffers (footprint identical to R3's known-good layout: P aliases drug)
  float* hs   = (float*)alloc((size_t)ND * CDIM * 4);        // reused as hidden hi/lo
  float* drug = (float*)alloc((size_t)ND * CDIM * 4);        // reused as split-K P
  float* c3   = (float*)alloc((size_t)BATCH * 2 * CDIM * 4);
  float* P    = drug;  // alias: P live only before gat_aggregate and after hidden_build
  u16* hid_hi = (u16*)hs;                                    // hs dead after GAT
  u16* hid_lo = hid_hi + (size_t)BATCH * 4 * CDIM;
  // activation splits
  u16* xd_hi = (u16*)alloc((size_t)ND * FD * 2);
  u16* xd_lo = (u16*)alloc((size_t)ND * FD * 2);
  u16* cn_hi = (u16*)alloc((size_t)BATCH * 896 * 2);
  u16* cn_lo = (u16*)alloc((size_t)BATCH * 896 * 2);
  u16* c1_hi = (u16*)alloc((size_t)BATCH * 2048 * 2);        // shared with h1
  u16* c1_lo = (u16*)alloc((size_t)BATCH * 2048 * 2);
  u16* c2_hi = (u16*)alloc((size_t)BATCH * 512 * 2);         // shared with h2
  u16* c2_lo = (u16*)alloc((size_t)BATCH * 512 * 2);
  // transposed+split weights [N][Kpad]
  u16* wsrcT_hi = (u16*)alloc((size_t)CDIM * FD * 2);
  u16* wsrcT_lo = (u16*)alloc((size_t)CDIM * FD * 2);
  u16* r1T_hi = (u16*)alloc((size_t)2048 * 896 * 2);
  u16* r1T_lo = (u16*)alloc((size_t)2048 * 896 * 2);
  u16* r2T_hi = (u16*)alloc((size_t)512 * 2048 * 2);
  u16* r2T_lo = (u16*)alloc((size_t)512 * 2048 * 2);
  u16* r3T_hi = (u16*)alloc((size_t)1536 * 512 * 2);
  u16* r3T_lo = (u16*)alloc((size_t)1536 * 512 * 2);
  u16* raT_hi = (u16*)alloc((size_t)2048 * 3072 * 2);
  u16* raT_lo = (u16*)alloc((size_t)2048 * 3072 * 2);
  u16* rbT_hi = (u16*)alloc((size_t)512 * 2048 * 2);
  u16* rbT_lo = (u16*)alloc((size_t)512 * 2048 * 2);
  u16* rcT_hi = (u16*)alloc((size_t)768 * 512 * 2);
  u16* rcT_lo = (u16*)alloc((size_t)768 * 512 * 2);
  // GAT scalars / CSR
  float* es  = (float*)alloc((size_t)ND * 4);
  float* ed  = (float*)alloc((size_t)ND * 4);
  float* wsv = (float*)alloc(FD * 4);
  float* wdv = (float*)alloc(FD * 4);
  int* counts  = (int*)alloc((size_t)ND * 4);
  int* offsets = (int*)alloc((size_t)(ND + 1) * 4);
  int* cursor  = (int*)alloc((size_t)ND * 4);
  int* slots   = (int*)alloc((size_t)(E_DD + ND) * 4);
  (void)ws_size; (void)n_in; (void)in_sizes; (void)out_size;

  // --- weight prep: 7 transposes in one launch ---
  TPack tp;
  tp.d[0] = {W_src_dd, wsrcT_hi, wsrcT_lo, 256, 768, 256, 0};
  tp.d[1] = {red1_w, r1T_hi, r1T_lo, 890, 2048, 896, 192};
  tp.d[2] = {red2_w, r2T_hi, r2T_lo, 2048, 512, 2048, 1984};
  tp.d[3] = {red3_w, r3T_hi, r3T_lo, 512, 1536, 512, 3008};
  tp.d[4] = {r2a_w, raT_hi, raT_lo, 3072, 2048, 3072, 3776};
  tp.d[5] = {r2b_w, rbT_hi, rbT_lo, 2048, 512, 2048, 9920};
  tp.d[6] = {r2c_w, rcT_hi, rcT_lo, 512, 768, 512, 10944};
  multi_transpose<<<11328, dim3(32, 8), 0, stream>>>(tp);

  // --- GAT scalar prep (independent of cell MLP) ---
  wvec_kernel<<<FD, 256, 0, stream>>>(W_src_dd, W_dst_dd, a_src_dd, a_dst_dd, wsv, wdv);
  split_esed<<<ND * FD / 1024, 256, 0, stream>>>(x_drug, wsv, wdv, xd_hi, xd_lo, es, ed);

  // --- cell MLP FIRST (its split-K uses P = drug space, drug not yet live) ---
  l2norm_split<<<BATCH, 256, 0, stream>>>(cellf, cn_hi, cn_lo, 890, 896);
  mfma_gemm<1, 1, 1, 1><<<dim3(BATCH / 128, 2048 / 128), 256, 0, stream>>>(
      cn_hi, cn_lo, r1T_hi, r1T_lo, red1_b, nullptr, c1_hi, c1_lo, BATCH, 2048, 896);
  mfma_gemm<4, 0, 0, 0><<<dim3(BATCH / 128, 512 / 128, 4), 256, 0, stream>>>(
      c1_hi, c1_lo, r2T_hi, r2T_lo, nullptr, P, nullptr, nullptr, BATCH, 512, 2048);
  reduce_split_ks<4><<<BATCH * 512 / 1024, 256, 0, stream>>>(P, red2_b, c2_hi, c2_lo, BATCH, 512);
  mfma_gemm<1, 0, 1, 1><<<dim3(BATCH / 128, 1536 / 128), 256, 0, stream>>>(
      c2_hi, c2_lo, r3T_hi, r3T_lo, red3_b, c3, nullptr, nullptr, BATCH, 1536, 512);

  // --- GAT (P dead; gat_aggregate overwrites drug/P space) ---
  mfma_gemm<1, 0, 0, 0><<<dim3(ND / 128, CDIM / 128), 256, 0, stream>>>(
      xd_hi, xd_lo, wsrcT_hi, wsrcT_lo, nullptr, hs, nullptr, nullptr, ND, CDIM, FD);
  count_init<<<ND / 256, 256, 0, stream>>>(counts);
  count_edges<<<E_DD / 256, 256, 0, stream>>>(dd_dst, counts);
  scan_kernel<<<1, 512, 0, stream>>>(counts, offsets);
  selfloop_init<<<ND / 256, 256, 0, stream>>>(offsets, cursor, slots);
  scatter_edges<<<E_DD / 256, 256, 0, stream>>>(dd_src, dd_dst, cursor, slots);
  gat_aggregate<<<ND / 4, 256, 0, stream>>>(hs, es, ed, offsets, slots, b_dd, drug);

  // --- gather + concat + l2norm -> split (hidden aliases hs; last read of drug) ---
  hidden_build_split<<<BATCH, 256, 0, stream>>>(drug, c3, drug1_id, drug2_id, hid_hi, hid_lo);

  // --- head MLP (drug dead; P = drug space reusable) ---
  mfma_gemm<1, 1, 1, 1><<<dim3(BATCH / 128, 2048 / 128), 256, 0, stream>>>(
      hid_hi, hid_lo, raT_hi, raT_lo, r2a_b, nullptr, c1_hi, c1_lo, BATCH, 2048, 3072);
  mfma_gemm<4, 0, 0, 0><<<dim3(BATCH / 128, 512 / 128, 4), 256, 0, stream>>>(
      c1_hi, c1_lo, rbT_hi, rbT_lo, nullptr, P, nullptr, nullptr, BATCH, 512, 2048);
  reduce_split_ks<4><<<BATCH * 512 / 1024, 256, 0, stream>>>(P, r2b_b, c2_hi, c2_lo, BATCH, 512);
  mfma_gemm<2, 0, 0, 0><<<dim3(BATCH / 128, CDIM / 128, 2), 256, 0, stream>>>(
      c2_hi, c2_lo, rcT_hi, rcT_lo, nullptr, P, nullptr, nullptr, BATCH, CDIM, 512);
  reduce_cls<<<BATCH / 4, 256, 0, stream>>>(P, r2c_b, cls_w, cls_b, out);
}

// Round 6
// 696.418 us; speedup vs baseline: 4.2370x; 1.0086x over previous
//
#include <hip/hip_runtime.h>
#include <cstdint>

#define ND 16384
#define BATCH 4096
#define CDIM 768
#define E_DD 131072
#define FD 256

typedef unsigned short u16;
typedef u16 u16x4 __attribute__((ext_vector_type(4)));
typedef u16 u16x8 __attribute__((ext_vector_type(8)));
typedef short s16x8 __attribute__((ext_vector_type(8)));
typedef float f32x4 __attribute__((ext_vector_type(4)));
typedef float f32x16 __attribute__((ext_vector_type(16)));

__device__ __forceinline__ u16 f2bf(float x) {
  union { float f; uint32_t u; } v; v.f = x;
  uint32_t r = v.u + 0x7fffu + ((v.u >> 16) & 1u);
  return (u16)(r >> 16);
}
__device__ __forceinline__ float bf2f(u16 h) {
  union { float f; uint32_t u; } v; v.u = ((uint32_t)h) << 16;
  return v.f;
}
// (hi << 16) | lo ; hi = bf16(x), lo = bf16(x - hi)
__device__ __forceinline__ uint32_t split2p(float x) {
  u16 h = f2bf(x);
  u16 l = f2bf(x - bf2f(h));
  return ((uint32_t)h << 16) | l;
}

// ---------------------------------------------------------------------------
// bf16x3 MFMA GEMM, 128x128 tile, BK=32, 4 waves (2x2), 32x32x16 MFMA.
// A hi/lo [M][K]; B hi/lo transposed [N][K].
// LDS: pitch KP=40 u16 + XOR kunit swizzle (phys_u = u ^ ((row>>3)&3)) ->
// conflict-free ds_read_b128 / ds_write_b128 for both 16- and 32-row patterns.
// KS>1: split-K partial mode — blockIdx.z selects K-chunk, writes fp32
// partial at Cf + z*M*N, no bias/relu/split.
// ---------------------------------------------------------------------------
#define KP 40

template <int KS, int OUT_SPLIT, int RELU, int BIAS>
__global__ __launch_bounds__(256) void mfma_gemm(
    const u16* __restrict__ Ahi, const u16* __restrict__ Alo,
    const u16* __restrict__ Bhi, const u16* __restrict__ Blo,
    const float* __restrict__ bias,
    float* __restrict__ Cf, u16* __restrict__ Chi, u16* __restrict__ Clo,
    int M, int N, int K) {
  constexpr int BM = 128, BN = 128;
  constexpr int ASEG = BM / 64;
  constexpr int BSEG = BN / 64;
  __shared__ __align__(16) u16 As[2][BM][KP];
  __shared__ __align__(16) u16 Bs[2][BN][KP];

  const int t = threadIdx.x;
  const int bm0 = blockIdx.x * BM, bn0 = blockIdx.y * BN;
  const int wid = t >> 6, lane = t & 63;
  const int m32 = lane & 31, kh = lane >> 5;
  const int wm0 = (wid >> 1) * 64;  // wave tile 64x64
  const int wn0 = (wid & 1) * 64;

  const int chunk = K / KS;
  const int kbeg = (KS > 1) ? (int)blockIdx.z * chunk : 0;
  const int kend = kbeg + chunk;

  f32x16 acc[2][2];
#pragma unroll
  for (int i = 0; i < 2; ++i)
#pragma unroll
    for (int j = 0; j < 2; ++j)
#pragma unroll
      for (int e = 0; e < 16; ++e) acc[i][j][e] = 0.f;

  u16x8 pAh[ASEG], pAl[ASEG], pBh[BSEG], pBl[BSEG];

#pragma unroll
  for (int c = 0; c < ASEG; ++c) {
    int s = t + 256 * c, row = s >> 2, kq = (s & 3) * 8;
    size_t off = (size_t)(bm0 + row) * K + kbeg + kq;
    pAh[c] = *(const u16x8*)(Ahi + off);
    pAl[c] = *(const u16x8*)(Alo + off);
  }
#pragma unroll
  for (int c = 0; c < BSEG; ++c) {
    int s = t + 256 * c, row = s >> 2, kq = (s & 3) * 8;
    size_t off = (size_t)(bn0 + row) * K + kbeg + kq;
    pBh[c] = *(const u16x8*)(Bhi + off);
    pBl[c] = *(const u16x8*)(Blo + off);
  }

  for (int k0 = kbeg;;) {
    __syncthreads();
#pragma unroll
    for (int c = 0; c < ASEG; ++c) {
      int s = t + 256 * c, row = s >> 2;
      int pu = (s & 3) ^ ((row >> 3) & 3);  // swizzled kunit
      *(u16x8*)&As[0][row][pu * 8] = pAh[c];
      *(u16x8*)&As[1][row][pu * 8] = pAl[c];
    }
#pragma unroll
    for (int c = 0; c < BSEG; ++c) {
      int s = t + 256 * c, row = s >> 2;
      int pu = (s & 3) ^ ((row >> 3) & 3);
      *(u16x8*)&Bs[0][row][pu * 8] = pBh[c];
      *(u16x8*)&Bs[1][row][pu * 8] = pBl[c];
    }
    __syncthreads();

    int kn = k0 + 32;
    if (kn < kend) {
#pragma unroll
      for (int c = 0; c < ASEG; ++c) {
        int s = t + 256 * c, row = s >> 2, kq = (s & 3) * 8;
        size_t off = (size_t)(bm0 + row) * K + kn + kq;
        pAh[c] = *(const u16x8*)(Ahi + off);
        pAl[c] = *(const u16x8*)(Alo + off);
      }
#pragma unroll
      for (int c = 0; c < BSEG; ++c) {
        int s = t + 256 * c, row = s >> 2, kq = (s & 3) * 8;
        size_t off = (size_t)(bn0 + row) * K + kn + kq;
        pBh[c] = *(const u16x8*)(Bhi + off);
        pBl[c] = *(const u16x8*)(Blo + off);
      }
    }

    // two k-steps of 16 within the 32-wide tile
#pragma unroll
    for (int ks = 0; ks < 2; ++ks) {
      const int u = ks * 2 + kh;  // logical kunit for this lane
      s16x8 ah[2], al[2], bh[2], bl[2];
#pragma unroll
      for (int mi = 0; mi < 2; ++mi) {
        int row = wm0 + mi * 32 + m32;
        int pu = u ^ ((row >> 3) & 3);
        ah[mi] = *(const s16x8*)&As[0][row][pu * 8];
        al[mi] = *(const s16x8*)&As[1][row][pu * 8];
      }
#pragma unroll
      for (int ni = 0; ni < 2; ++ni) {
        int row = wn0 + ni * 32 + m32;
        int pu = u ^ ((row >> 3) & 3);
        bh[ni] = *(const s16x8*)&Bs[0][row][pu * 8];
        bl[ni] = *(const s16x8*)&Bs[1][row][pu * 8];
      }
#pragma unroll
      for (int mi = 0; mi < 2; ++mi)
#pragma unroll
        for (int ni = 0; ni < 2; ++ni) {
          acc[mi][ni] = __builtin_amdgcn_mfma_f32_32x32x16_bf16(
              ah[mi], bh[ni], acc[mi][ni], 0, 0, 0);
          acc[mi][ni] = __builtin_amdgcn_mfma_f32_32x32x16_bf16(
              ah[mi], bl[ni], acc[mi][ni], 0, 0, 0);
          acc[mi][ni] = __builtin_amdgcn_mfma_f32_32x32x16_bf16(
              al[mi], bh[ni], acc[mi][ni], 0, 0, 0);
        }
    }
    k0 = kn;
    if (k0 >= kend) break;
  }

  // 32x32 C/D layout (m74/m101): col = lane&31, row = (reg&3) + 8*(reg>>2) + 4*(lane>>5)
  float* Cp = (KS > 1) ? Cf + (size_t)blockIdx.z * M * N : Cf;
#pragma unroll
  for (int mi = 0; mi < 2; ++mi) {
#pragma unroll
    for (int ni = 0; ni < 2; ++ni) {
      int colb = bn0 + wn0 + ni * 32 + m32;
      float bv = BIAS ? bias[colb] : 0.f;
#pragma unroll
      for (int reg = 0; reg < 16; ++reg) {
        int row = bm0 + wm0 + mi * 32 + (reg & 3) + 8 * (reg >> 2) + 4 * kh;
        float v = acc[mi][ni][reg] + bv;
        if (RELU) v = fmaxf(v, 0.f);
        size_t o = (size_t)row * N + colb;
        if (OUT_SPLIT) {
          uint32_t p = split2p(v);
          Chi[o] = (u16)(p >> 16);
          Clo[o] = (u16)(p & 0xffffu);
        } else {
          Cp[o] = v;
        }
      }
    }
  }
}

// ---------------------------------------------------------------------------
// Split-K reduce: sum KS fp32 partials, +bias, relu, bf16 hi/lo split.
// ---------------------------------------------------------------------------
template <int KS>
__global__ void reduce_split_ks(const float* __restrict__ P,
                                const float* __restrict__ bias,
                                u16* __restrict__ Chi, u16* __restrict__ Clo,
                                int M, int N) {
  int i = blockIdx.x * 256 + threadIdx.x;
  int total = (M * N) >> 2;
  if (i >= total) return;
  f32x4 s = ((const f32x4*)P)[i];
#pragma unroll
  for (int z = 1; z < KS; ++z) s += ((const f32x4*)P)[(size_t)z * total + i];
  int col = (i * 4) % N;
  f32x4 bv = *(const f32x4*)(bias + col);
  u16x4 h, l;
#pragma unroll
  for (int e = 0; e < 4; ++e) {
    float v = fmaxf(s[e] + bv[e], 0.f);
    uint32_t p = split2p(v);
    h[e] = (u16)(p >> 16);
    l[e] = (u16)(p & 0xffffu);
  }
  *(u16x4*)&Chi[i * 4] = h;
  *(u16x4*)&Clo[i * 4] = l;
}

// ---------------------------------------------------------------------------
// r2c reduce fused with classifier: h = relu(P0+P1+bias) per row (768),
// out[row] = h @ cls_w + cls_b. One wave per row.
// ---------------------------------------------------------------------------
__global__ void reduce_cls(const float* __restrict__ P,
                           const float* __restrict__ bias,
                           const float* __restrict__ clsw,
                           const float* __restrict__ clsb,
                           float* __restrict__ out) {
  int row = blockIdx.x * 4 + (threadIdx.x >> 6);
  int lane = threadIdx.x & 63;
  const f32x4* p0 = (const f32x4*)(P + (size_t)row * CDIM);
  const f32x4* p1 = (const f32x4*)(P + (size_t)BATCH * CDIM + (size_t)row * CDIM);
  float s0 = 0.f, s1 = 0.f;
#pragma unroll
  for (int i = 0; i < 3; ++i) {
    int c4 = lane + 64 * i;
    f32x4 a = p0[c4] + p1[c4];
    f32x4 bv = *(const f32x4*)(bias + c4 * 4);
#pragma unroll
    for (int e = 0; e < 4; ++e) {
      float h = fmaxf(a[e] + bv[e], 0.f);
      int c = c4 * 4 + e;
      s0 = fmaf(h, clsw[c * 2 + 0], s0);
      s1 = fmaf(h, clsw[c * 2 + 1], s1);
    }
  }
#pragma unroll
  for (int m = 32; m; m >>= 1) {
    s0 += __shfl_xor(s0, m);
    s1 += __shfl_xor(s1, m);
  }
  if (lane == 0) {
    out[row * 2 + 0] = s0 + clsb[0];
    out[row * 2 + 1] = s1 + clsb[1];
  }
}

// ---------------------------------------------------------------------------
// Multi-matrix weight transpose + bf16 split: W fp32 [K][N] -> [N][Kpad].
// ---------------------------------------------------------------------------
struct TDesc {
  const float* W;
  u16* Th;
  u16* Tl;
  int K, N, Kpad, start;
};
struct TPack { TDesc d[7]; };

__global__ void multi_transpose(TPack p) {
  __shared__ float tile[32][33];
  int b = blockIdx.x;
  int mi = 0;
#pragma unroll
  for (int i = 1; i < 7; ++i)
    if (b >= p.d[i].start) mi = i;
  TDesc dd = p.d[mi];
  int rel = b - dd.start;
  int tilesX = dd.Kpad / 32;
  int k0 = (rel % tilesX) * 32, n0 = (rel / tilesX) * 32;
  int tx = threadIdx.x, ty = threadIdx.y;
#pragma unroll
  for (int i = 0; i < 4; ++i) {
    int k = k0 + ty + 8 * i, n = n0 + tx;
    tile[ty + 8 * i][tx] = (k < dd.K && n < dd.N) ? dd.W[(size_t)k * dd.N + n] : 0.f;
  }
  __syncthreads();
#pragma unroll
  for (int i = 0; i < 4; ++i) {
    int n = n0 + ty + 8 * i, k = k0 + tx;
    if (n < dd.N) {
      uint32_t pk = split2p(tile[tx][ty + 8 * i]);
      dd.Th[(size_t)n * dd.Kpad + k] = (u16)(pk >> 16);
      dd.Tl[(size_t)n * dd.Kpad + k] = (u16)(pk & 0xffffu);
    }
  }
}

// ---------------------------------------------------------------------------
// wsv[k] = sum_c W_src[k,c]*a_src[c] ; wdv[k] = sum_c W_dst[k,c]*a_dst[c]
// ---------------------------------------------------------------------------
__global__ void wvec_kernel(const float* __restrict__ Wsrc,
                            const float* __restrict__ Wdst,
                            const float* __restrict__ a_s,
                            const float* __restrict__ a_d,
                            float* __restrict__ wsv, float* __restrict__ wdv) {
  int k = blockIdx.x;
  int t = threadIdx.x;
  __shared__ float rs[256], rd[256];
  float s = 0.f, d = 0.f;
  for (int c = t; c < CDIM; c += 256) {
    s += Wsrc[(size_t)k * CDIM + c] * a_s[c];
    d += Wdst[(size_t)k * CDIM + c] * a_d[c];
  }
  rs[t] = s; rd[t] = d;
  __syncthreads();
  for (int st = 128; st; st >>= 1) {
    if (t < st) { rs[t] += rs[t + st]; rd[t] += rd[t + st]; }
    __syncthreads();
  }
  if (t == 0) { wsv[k] = rs[0]; wdv[k] = rd[0]; }
}

// ---------------------------------------------------------------------------
// Fused: x_drug bf16 hi/lo split + es/ed row dots. One wave per row.
// ---------------------------------------------------------------------------
__global__ void split_esed(const float* __restrict__ x,
                           const float* __restrict__ wsv,
                           const float* __restrict__ wdv,
                           u16* __restrict__ hi, u16* __restrict__ lo,
                           float* __restrict__ es, float* __restrict__ ed) {
  int i = blockIdx.x * 256 + threadIdx.x;  // float4 index
  int lane = threadIdx.x & 63;
  int row = i >> 6;
  int c4 = lane * 4;
  f32x4 v = ((const f32x4*)x)[i];
  u16x4 h, l;
#pragma unroll
  for (int e = 0; e < 4; ++e) {
    uint32_t p = split2p(v[e]);
    h[e] = (u16)(p >> 16);
    l[e] = (u16)(p & 0xffffu);
  }
  *(u16x4*)&hi[i * 4] = h;
  *(u16x4*)&lo[i * 4] = l;
  f32x4 ws = *(const f32x4*)(wsv + c4);
  f32x4 wd = *(const f32x4*)(wdv + c4);
  float a = v[0] * ws[0] + v[1] * ws[1] + v[2] * ws[2] + v[3] * ws[3];
  float b = v[0] * wd[0] + v[1] * wd[1] + v[2] * wd[2] + v[3] * wd[3];
#pragma unroll
  for (int m = 32; m; m >>= 1) {
    a += __shfl_xor(a, m);
    b += __shfl_xor(b, m);
  }
  if (lane == 0) { es[row] = a; ed[row] = b; }
}

// ---------------------------------------------------------------------------
// CSR build (dst-sorted, self loop at segment head)
// ---------------------------------------------------------------------------
__global__ void count_init(int* counts) {
  int i = blockIdx.x * 256 + threadIdx.x;
  if (i < ND) counts[i] = 1;
}
__global__ void count_edges(const int* __restrict__ dst, int* counts) {
  int e = blockIdx.x * 256 + threadIdx.x;
  if (e < E_DD) atomicAdd(&counts[dst[e]], 1);
}
__global__ void scan_kernel(const int* __restrict__ counts, int* __restrict__ offsets) {
  __shared__ int part[512];
  int t = threadIdx.x;
  int base = t * 32;
  int s = 0;
  for (int i = 0; i < 32; ++i) s += counts[base + i];
  part[t] = s;
  __syncthreads();
  if (t == 0) {
    int run = 0;
    for (int i = 0; i < 512; ++i) { int tmp = part[i]; part[i] = run; run += tmp; }
    offsets[ND] = run;
  }
  __syncthreads();
  int run = part[t];
  for (int i = 0; i < 32; ++i) { offsets[base + i] = run; run += counts[base + i]; }
}
__global__ void selfloop_init(const int* __restrict__ offsets, int* cursor, int* slots) {
  int d = blockIdx.x * 256 + threadIdx.x;
  if (d < ND) {
    int o = offsets[d];
    slots[o] = d;
    cursor[d] = o + 1;
  }
}
__global__ void scatter_edges(const int* __restrict__ src, const int* __restrict__ dst,
                              int* cursor, int* slots) {
  int e = blockIdx.x * 256 + threadIdx.x;
  if (e < E_DD) {
    int pos = atomicAdd(&cursor[dst[e]], 1);
    slots[pos] = src[e];
  }
}

// ---------------------------------------------------------------------------
// GAT aggregation: ONE WAVE per dst node (deg~9). Shuffle reductions,
// float4 column loads (768 = 64 lanes x 3 x float4).
// ---------------------------------------------------------------------------
__global__ __launch_bounds__(256) void gat_aggregate(
    const float* __restrict__ hs, const float* __restrict__ es,
    const float* __restrict__ ed, const int* __restrict__ offsets,
    const int* __restrict__ slots, const float* __restrict__ bias,
    float* __restrict__ out) {
  int d = blockIdx.x * 4 + (threadIdx.x >> 6);
  int lane = threadIdx.x & 63;
  int beg = offsets[d], end = offsets[d + 1];
  float edv = ed[d];
  float mx = -1e30f;
  for (int j = beg + lane; j < end; j += 64) {
    float e = es[slots[j]] + edv;
    e = e >= 0.f ? e : 0.2f * e;
    mx = fmaxf(mx, e);
  }
#pragma unroll
  for (int m = 32; m; m >>= 1) mx = fmaxf(mx, __shfl_xor(mx, m));
  float sm = 0.f;
  for (int j = beg + lane; j < end; j += 64) {
    float e = es[slots[j]] + edv;
    e = e >= 0.f ? e : 0.2f * e;
    sm += expf(e - mx);
  }
#pragma unroll
  for (int m = 32; m; m >>= 1) sm += __shfl_xor(sm, m);
  float inv = 1.f / (sm + 1e-16f);
  f32x4 a0 = {0.f, 0.f, 0.f, 0.f}, a1 = a0, a2 = a0;
  for (int j = beg; j < end; ++j) {
    int srcn = slots[j];
    float e = es[srcn] + edv;
    e = e >= 0.f ? e : 0.2f * e;
    float alpha = expf(e - mx) * inv;
    const f32x4* hrow = (const f32x4*)(hs + (size_t)srcn * CDIM);
    a0 += alpha * hrow[lane];
    a1 += alpha * hrow[lane + 64];
    a2 += alpha * hrow[lane + 128];
  }
  float* orow = out + (size_t)d * CDIM;
  const f32x4* bv = (const f32x4*)bias;
  f32x4 b0 = bv[lane], b1 = bv[lane + 64], b2 = bv[lane + 128];
  f32x4 o0, o1, o2;
#pragma unroll
  for (int e = 0; e < 4; ++e) {
    o0[e] = fmaxf(a0[e] + b0[e], 0.f);
    o1[e] = fmaxf(a1[e] + b1[e], 0.f);
    o2[e] = fmaxf(a2[e] + b2[e], 0.f);
  }
  ((f32x4*)orow)[lane] = o0;
  ((f32x4*)orow)[lane + 64] = o1;
  ((f32x4*)orow)[lane + 128] = o2;
}

// ---------------------------------------------------------------------------
// cell l2norm -> bf16 hi/lo [BATCH][Lp], zero pad L..Lp
// ---------------------------------------------------------------------------
__global__ void l2norm_split(const float* __restrict__ in, u16* __restrict__ hi,
                             u16* __restrict__ lo, int L, int Lp) {
  int row = blockIdx.x;
  int t = threadIdx.x;
  __shared__ float red[256];
  const float* irow = in + (size_t)row * L;
  float s = 0.f;
  for (int c = t; c < L; c += 256) { float v = irow[c]; s += v * v; }
  red[t] = s;
  __syncthreads();
  for (int st = 128; st; st >>= 1) {
    if (t < st) red[t] += red[t + st];
    __syncthreads();
  }
  float inv = 1.f / fmaxf(sqrtf(red[0]), 1e-12f);
  for (int c = t; c < Lp; c += 256) {
    float v = (c < L) ? irow[c] * inv : 0.f;
    uint32_t p = split2p(v);
    hi[(size_t)row * Lp + c] = (u16)(p >> 16);
    lo[(size_t)row * Lp + c] = (u16)(p & 0xffffu);
  }
}

// hidden = l2norm(concat(drug[d1], drug[d2], cell3)) -> bf16 hi/lo [B][3072]
__global__ __launch_bounds__(256) void hidden_build_split(
    const float* __restrict__ drug, const float* __restrict__ c3,
    const int* __restrict__ d1, const int* __restrict__ d2,
    u16* __restrict__ hhi, u16* __restrict__ hlo) {
  int row = blockIdx.x;
  int t = threadIdx.x;
  const float* s1 = drug + (size_t)d1[row] * CDIM;
  const float* s2 = drug + (size_t)d2[row] * CDIM;
  const float* s3 = c3 + (size_t)row * (2 * CDIM);
  float vals[12];
  float ss = 0.f;
#pragma unroll
  for (int i = 0; i < 12; ++i) {
    int c = t + 256 * i;
    float v;
    if (i < 3)      v = s1[c];
    else if (i < 6) v = s2[c - CDIM];
    else            v = s3[c - 2 * CDIM];
    vals[i] = v;
    ss += v * v;
  }
  __shared__ float red[256];
  red[t] = ss;
  __syncthreads();
  for (int st = 128; st; st >>= 1) {
    if (t < st) red[t] += red[t + st];
    __syncthreads();
  }
  float inv = 1.f / fmaxf(sqrtf(red[0]), 1e-12f);
  u16* hrow_h = hhi + (size_t)row * (4 * CDIM);
  u16* hrow_l = hlo + (size_t)row * (4 * CDIM);
#pragma unroll
  for (int i = 0; i < 12; ++i) {
    uint32_t p = split2p(vals[i] * inv);
    hrow_h[t + 256 * i] = (u16)(p >> 16);
    hrow_l[t + 256 * i] = (u16)(p & 0xffffu);
  }
}

// ---------------------------------------------------------------------------
extern "C" void kernel_launch(void* const* d_in, const int* in_sizes, int n_in,
                              void* d_out, int out_size, void* d_ws, size_t ws_size,
                              hipStream_t stream) {
  const float* x_drug   = (const float*)d_in[0];
  const float* cellf    = (const float*)d_in[2];
  const float* W_src_dd = (const float*)d_in[3];
  const float* W_dst_dd = (const float*)d_in[4];
  const float* a_src_dd = (const float*)d_in[5];
  const float* a_dst_dd = (const float*)d_in[6];
  const float* b_dd     = (const float*)d_in[7];
  const float* red1_w = (const float*)d_in[18];
  const float* red1_b = (const float*)d_in[19];
  const float* red2_w = (const float*)d_in[20];
  const float* red2_b = (const float*)d_in[21];
  const float* red3_w = (const float*)d_in[22];
  const float* red3_b = (const float*)d_in[23];
  const float* r2a_w  = (const float*)d_in[24];
  const float* r2a_b  = (const float*)d_in[25];
  const float* r2b_w  = (const float*)d_in[26];
  const float* r2b_b  = (const float*)d_in[27];
  const float* r2c_w  = (const float*)d_in[28];
  const float* r2c_b  = (const float*)d_in[29];
  const float* cls_w  = (const float*)d_in[30];
  const float* cls_b  = (const float*)d_in[31];
  const int* drug1_id = (const int*)d_in[32];
  const int* drug2_id = (const int*)d_in[33];
  const int* ei_dd    = (const int*)d_in[34];
  float* out = (float*)d_out;

  const int* dd_src = ei_dd;
  const int* dd_dst = ei_dd + E_DD;

  char* w = (char*)d_ws;
  size_t off = 0;
  auto alloc = [&](size_t bytes) -> char* {
    char* p = w + off;
    off = (off + bytes + 255) & ~(size_t)255;
    return p;
  };
  // fp32 buffers (P aliases drug; live ranges disjoint by schedule below)
  float* hs   = (float*)alloc((size_t)ND * CDIM * 4);        // reused as hidden hi/lo
  float* drug = (float*)alloc((size_t)ND * CDIM * 4);        // reused as split-K P
  float* c3   = (float*)alloc((size_t)BATCH * 2 * CDIM * 4);
  float* P    = drug;
  u16* hid_hi = (u16*)hs;                                    // hs dead after GAT
  u16* hid_lo = hid_hi + (size_t)BATCH * 4 * CDIM;
  // activation splits
  u16* xd_hi = (u16*)alloc((size_t)ND * FD * 2);
  u16* xd_lo = (u16*)alloc((size_t)ND * FD * 2);
  u16* cn_hi = (u16*)alloc((size_t)BATCH * 896 * 2);
  u16* cn_lo = (u16*)alloc((size_t)BATCH * 896 * 2);
  u16* c1_hi = (u16*)alloc((size_t)BATCH * 2048 * 2);        // shared with h1
  u16* c1_lo = (u16*)alloc((size_t)BATCH * 2048 * 2);
  u16* c2_hi = (u16*)alloc((size_t)BATCH * 512 * 2);         // shared with h2
  u16* c2_lo = (u16*)alloc((size_t)BATCH * 512 * 2);
  // transposed+split weights [N][Kpad]
  u16* wsrcT_hi = (u16*)alloc((size_t)CDIM * FD * 2);
  u16* wsrcT_lo = (u16*)alloc((size_t)CDIM * FD * 2);
  u16* r1T_hi = (u16*)alloc((size_t)2048 * 896 * 2);
  u16* r1T_lo = (u16*)alloc((size_t)2048 * 896 * 2);
  u16* r2T_hi = (u16*)alloc((size_t)512 * 2048 * 2);
  u16* r2T_lo = (u16*)alloc((size_t)512 * 2048 * 2);
  u16* r3T_hi = (u16*)alloc((size_t)1536 * 512 * 2);
  u16* r3T_lo = (u16*)alloc((size_t)1536 * 512 * 2);
  u16* raT_hi = (u16*)alloc((size_t)2048 * 3072 * 2);
  u16* raT_lo = (u16*)alloc((size_t)2048 * 3072 * 2);
  u16* rbT_hi = (u16*)alloc((size_t)512 * 2048 * 2);
  u16* rbT_lo = (u16*)alloc((size_t)512 * 2048 * 2);
  u16* rcT_hi = (u16*)alloc((size_t)768 * 512 * 2);
  u16* rcT_lo = (u16*)alloc((size_t)768 * 512 * 2);
  // GAT scalars / CSR
  float* es  = (float*)alloc((size_t)ND * 4);
  float* ed  = (float*)alloc((size_t)ND * 4);
  float* wsv = (float*)alloc(FD * 4);
  float* wdv = (float*)alloc(FD * 4);
  int* counts  = (int*)alloc((size_t)ND * 4);
  int* offsets = (int*)alloc((size_t)(ND + 1) * 4);
  int* cursor  = (int*)alloc((size_t)ND * 4);
  int* slots   = (int*)alloc((size_t)(E_DD + ND) * 4);
  (void)ws_size; (void)n_in; (void)in_sizes; (void)out_size;

  // --- weight prep: 7 transposes in one launch ---
  TPack tp;
  tp.d[0] = {W_src_dd, wsrcT_hi, wsrcT_lo, 256, 768, 256, 0};
  tp.d[1] = {red1_w, r1T_hi, r1T_lo, 890, 2048, 896, 192};
  tp.d[2] = {red2_w, r2T_hi, r2T_lo, 2048, 512, 2048, 1984};
  tp.d[3] = {red3_w, r3T_hi, r3T_lo, 512, 1536, 512, 3008};
  tp.d[4] = {r2a_w, raT_hi, raT_lo, 3072, 2048, 3072, 3776};
  tp.d[5] = {r2b_w, rbT_hi, rbT_lo, 2048, 512, 2048, 9920};
  tp.d[6] = {r2c_w, rcT_hi, rcT_lo, 512, 768, 512, 10944};
  multi_transpose<<<11328, dim3(32, 8), 0, stream>>>(tp);

  // --- GAT scalar prep ---
  wvec_kernel<<<FD, 256, 0, stream>>>(W_src_dd, W_dst_dd, a_src_dd, a_dst_dd, wsv, wdv);
  split_esed<<<ND * FD / 1024, 256, 0, stream>>>(x_drug, wsv, wdv, xd_hi, xd_lo, es, ed);

  // --- cell MLP FIRST (its split-K uses P = drug space, drug not yet live) ---
  l2norm_split<<<BATCH, 256, 0, stream>>>(cellf, cn_hi, cn_lo, 890, 896);
  mfma_gemm<1, 1, 1, 1><<<dim3(BATCH / 128, 2048 / 128), 256, 0, stream>>>(
      cn_hi, cn_lo, r1T_hi, r1T_lo, red1_b, nullptr, c1_hi, c1_lo, BATCH, 2048, 896);
  mfma_gemm<4, 0, 0, 0><<<dim3(BATCH / 128, 512 / 128, 4), 256, 0, stream>>>(
      c1_hi, c1_lo, r2T_hi, r2T_lo, nullptr, P, nullptr, nullptr, BATCH, 512, 2048);
  reduce_split_ks<4><<<BATCH * 512 / 1024, 256, 0, stream>>>(P, red2_b, c2_hi, c2_lo, BATCH, 512);
  mfma_gemm<1, 0, 1, 1><<<dim3(BATCH / 128, 1536 / 128), 256, 0, stream>>>(
      c2_hi, c2_lo, r3T_hi, r3T_lo, red3_b, c3, nullptr, nullptr, BATCH, 1536, 512);

  // --- GAT (P dead; gat_aggregate overwrites drug/P space) ---
  mfma_gemm<1, 0, 0, 0><<<dim3(ND / 128, CDIM / 128), 256, 0, stream>>>(
      xd_hi, xd_lo, wsrcT_hi, wsrcT_lo, nullptr, hs, nullptr, nullptr, ND, CDIM, FD);
  count_init<<<ND / 256, 256, 0, stream>>>(counts);
  count_edges<<<E_DD / 256, 256, 0, stream>>>(dd_dst, counts);
  scan_kernel<<<1, 512, 0, stream>>>(counts, offsets);
  selfloop_init<<<ND / 256, 256, 0, stream>>>(offsets, cursor, slots);
  scatter_edges<<<E_DD / 256, 256, 0, stream>>>(dd_src, dd_dst, cursor, slots);
  gat_aggregate<<<ND / 4, 256, 0, stream>>>(hs, es, ed, offsets, slots, b_dd, drug);

  // --- gather + concat + l2norm -> split (hidden aliases hs; last read of drug) ---
  hidden_build_split<<<BATCH, 256, 0, stream>>>(drug, c3, drug1_id, drug2_id, hid_hi, hid_lo);

  // --- head MLP (drug dead; P = drug space reusable) ---
  mfma_gemm<1, 1, 1, 1><<<dim3(BATCH / 128, 2048 / 128), 256, 0, stream>>>(
      hid_hi, hid_lo, raT_hi, raT_lo, r2a_b, nullptr, c1_hi, c1_lo, BATCH, 2048, 3072);
  mfma_gemm<4, 0, 0, 0><<<dim3(BATCH / 128, 512 / 128, 4), 256, 0, stream>>>(
      c1_hi, c1_lo, rbT_hi, rbT_lo, nullptr, P, nullptr, nullptr, BATCH, 512, 2048);
  reduce_split_ks<4><<<BATCH * 512 / 1024, 256, 0, stream>>>(P, r2b_b, c2_hi, c2_lo, BATCH, 512);
  mfma_gemm<2, 0, 0, 0><<<dim3(BATCH / 128, CDIM / 128, 2), 256, 0, stream>>>(
      c2_hi, c2_lo, rcT_hi, rcT_lo, nullptr, P, nullptr, nullptr, BATCH, CDIM, 512);
  reduce_cls<<<BATCH / 4, 256, 0, stream>>>(P, r2c_b, cls_w, cls_b, out);
}